// Round 1
// 788.324 us; speedup vs baseline: 2.1394x; 2.1394x over previous
//
#include <hip/hip_runtime.h>
#include <hip/hip_bf16.h>

// ---------------------------------------------------------------------------
// up_deeplabv3Head — round 4: repacked-operand GEMM engine for the four
// heavy K=4096 convs (a0/a1/a2/a3). One-time device repack of W -> [tap][o][c]
// bf16 and x -> X2[p][c] bf16, then a double-buffered conv_gemm using
// global_load_lds(16B) staging with XOR-swizzled LDS reads and zero-page
// OOB redirection. Old conv_mfma kept for rf1/rf2/r2/ap and as a full
// fallback when ws_size is too small for the repack buffers.
// ---------------------------------------------------------------------------

typedef unsigned short u16;
typedef short bf16x8 __attribute__((ext_vector_type(8)));
typedef float f32x4  __attribute__((ext_vector_type(4)));
typedef u16   u16x8  __attribute__((ext_vector_type(8)));

__device__ __forceinline__ float bf2f(u16 u) {
    return __uint_as_float(((unsigned int)u) << 16);
}
__device__ __forceinline__ u16 f2bf(float f) {   // round-to-nearest-even
    unsigned u = __float_as_uint(f);
    return (u16)((u + 0x7FFFu + ((u >> 16) & 1u)) >> 16);
}
// flag f32: 1 -> storage fp32, 0 -> storage bf16
__device__ __forceinline__ float loadv(const void* p, long i, int f32) {
    return f32 ? ((const float*)p)[i] : bf2f(((const u16*)p)[i]);
}
__device__ __forceinline__ u16 loadbf(const void* p, long i, int f32) {
    return f32 ? f2bf(((const float*)p)[i]) : ((const u16*)p)[i];
}

__device__ __forceinline__ void gload16(const u16* g, u16* l) {
    __builtin_amdgcn_global_load_lds(
        (const __attribute__((address_space(1))) unsigned int*)(g),
        (__attribute__((address_space(3))) unsigned int*)(l), 16, 0, 0);
}

// ---------------------------------------------------------------------------
// dtype probe (verified): bf16-stored N(0,1) has ~0 large-exponent words.
// ---------------------------------------------------------------------------
__global__ __launch_bounds__(256) void detect_kernel(
    const u16* __restrict__ c1, int* __restrict__ flag)
{
    __shared__ int cnt;
    if (threadIdx.x == 0) cnt = 0;
    __syncthreads();
    int local = 0;
    for (int i = threadIdx.x; i < 16384; i += 256) {
        u16 u = c1[i];
        if ((u & 0x7F80) >= 0x4F00) local++;
    }
    atomicAdd(&cnt, local);
    __syncthreads();
    if (threadIdx.x == 0) flag[0] = (cnt > 256) ? 1 : 0;
}

__global__ __launch_bounds__(256) void zero_kernel(float* __restrict__ p, int n)
{
    for (int g = blockIdx.x * 256 + threadIdx.x; g < n; g += gridDim.x * 256)
        p[g] = 0.f;
}

// ---------------------------------------------------------------------------
// Repack kernels (one-time per launch, flag-adaptive)
// ---------------------------------------------------------------------------

// x [4096][1024] (f32/bf16) -> X2 [1024][4096] bf16. 64x64 LDS tiles.
__global__ __launch_bounds__(256) void xpose_x(
    const void* __restrict__ x, u16* __restrict__ X2, const int* __restrict__ flag)
{
    __shared__ u16 T[64][72];
    const int f32 = flag[0];
    const int p0 = blockIdx.x * 64, c0 = blockIdx.y * 64;
    const int t = threadIdx.x;
    {
        int c = t >> 2, pq = (t & 3) * 16;
        if (f32) {
            const float* xp = (const float*)x + (long)(c0 + c) * 1024 + p0 + pq;
#pragma unroll
            for (int i = 0; i < 4; i++) {
                float4 v = *(const float4*)(xp + i * 4);
                T[pq + i * 4 + 0][c] = f2bf(v.x);
                T[pq + i * 4 + 1][c] = f2bf(v.y);
                T[pq + i * 4 + 2][c] = f2bf(v.z);
                T[pq + i * 4 + 3][c] = f2bf(v.w);
            }
        } else {
            const u16* xp = (const u16*)x + (long)(c0 + c) * 1024 + p0 + pq;
#pragma unroll
            for (int i = 0; i < 16; i++) T[pq + i][c] = xp[i];
        }
    }
    __syncthreads();
    {
        int p = t >> 2, cq = (t & 3) * 16;
        u16x8 v0, v1;
#pragma unroll
        for (int i = 0; i < 8; i++) { v0[i] = T[p][cq + i]; v1[i] = T[p][cq + 8 + i]; }
        *(u16x8*)&X2[(long)(p0 + p) * 4096 + c0 + cq] = v0;
        *(u16x8*)&X2[(long)(p0 + p) * 4096 + c0 + cq + 8] = v1;
    }
}

// W [512][4096][9] -> W2 [9][512][4096] bf16. One (o, 256-c chunk) per block.
__global__ __launch_bounds__(256) void xform_w9(
    const void* __restrict__ w, u16* __restrict__ W2, const int* __restrict__ flag)
{
    const int f32 = flag[0];
    const int o = blockIdx.y;
    const int c = blockIdx.x * 256 + threadIdx.x;
    const long src = ((long)o * 4096 + c) * 9;
    u16 v[9];
    if (f32) {
        const float* p = (const float*)w + src;
#pragma unroll
        for (int j = 0; j < 9; j++) v[j] = f2bf(p[j]);
    } else {
        const u16* p = (const u16*)w + src;
#pragma unroll
        for (int j = 0; j < 9; j++) v[j] = p[j];
    }
#pragma unroll
    for (int j = 0; j < 9; j++)
        W2[(long)j * (512 * 4096) + (long)o * 4096 + c] = v[j];
}

// generic 1-plane extract: Wo[o*4096+c] = w[o*ldi + off + c*st] as bf16
__global__ __launch_bounds__(256) void xform_w1(
    const void* __restrict__ w, u16* __restrict__ Wo, const int* __restrict__ flag,
    int ldi, int off, int st)
{
    const int f32 = flag[0];
    long g = (long)blockIdx.x * 256 + threadIdx.x;   // o*4096 + c
    int o = (int)(g >> 12), c = (int)(g & 4095);
    Wo[g] = loadbf(w, (long)o * ldi + off + (long)c * st, f32);
}

// ---------------------------------------------------------------------------
// conv_gemm: OUT[o,p] += sum_{t in mask, c} W2[t][o][c] * X2[p + shift(t)][c]
// 64o x 128px tile, 4 waves, double-buffered LDS, global_load_lds staging,
// XOR swizzle byte ^= ((byte>>7)&3)<<4 (involution; rows preserved).
// Split-K over gridDim.z, fp32 atomicAdd into pre-zeroed OUT. IW = 32.
// ---------------------------------------------------------------------------
__global__ __launch_bounds__(256, 4) void conv_gemm(
    const u16* __restrict__ W2, const u16* __restrict__ X2,
    const u16* __restrict__ zpage, float* __restrict__ OUT,
    int K, int O, int taps, int d)
{
    __shared__ __align__(16) u16 Ws[2][2048];   // 64 x 32 bf16 per buf
    __shared__ __align__(16) u16 Xs[2][4096];   // 128 x 32 bf16 per buf

    const int tid = threadIdx.x;
    const int bo = blockIdx.x, bp = blockIdx.y;
    const int kcs = K / gridDim.z;
    const int kb  = blockIdx.z * kcs;

    const int wave = tid >> 6, lane = tid & 63;
    const int quad = lane >> 4, l15 = lane & 15;

    // uniform valid-tap mask (tile rows bp*4 .. bp*4+3)
    int mask = 1;
    if (taps == 9) {
        const int ty0 = bp * 4;
        mask = 0;
        for (int t = 0; t < 9; t++) {
            int dy = (t / 3 - 1) * d;
            if (ty0 + 3 + dy >= 0 && ty0 + dy < 32) mask |= (1 << t);
        }
    }
    const int nIt = (kcs >> 5) * __popc(mask);

    // staging decode: physical dest byte b holds logical l = b ^ swz(b)
    const int bW  = tid * 16;
    const int lW  = bW ^ (((bW >> 7) & 3) << 4);
    const int s_wo = lW >> 6;
    const int s_wk = ((lW >> 4) & 3) * 8;
    const int bX0 = tid * 16;
    const int lX0 = bX0 ^ (((bX0 >> 7) & 3) << 4);
    const int p0r = lX0 >> 6, k0 = ((lX0 >> 4) & 3) * 8;
    const int bX1 = 4096 + tid * 16;
    const int lX1 = bX1 ^ (((bX1 >> 7) & 3) << 4);
    const int p1r = lX1 >> 6, k1 = ((lX1 >> 4) & 3) * 8;

    const long wplane = (long)O * K;
    const long wbase  = (long)(bo * 64 + s_wo) * K + s_wk;

    f32x4 acc[8];
#pragma unroll
    for (int j = 0; j < 8; j++) { f32x4 z = {0.f, 0.f, 0.f, 0.f}; acc[j] = z; }

    int aoff = (wave * 16 + l15) * 64 + quad * 16;
    aoff ^= ((aoff >> 7) & 3) << 4;

    int tt = __ffs(mask) - 1;
    int kc = kb;

    auto STAGE = [&](int buf) {
        int dy = 0, dx = 0;
        if (taps == 9) { dy = (tt / 3 - 1) * d; dx = (tt % 3 - 1) * d; }
        gload16(W2 + (long)tt * wplane + wbase + kc, &Ws[buf][tid * 8]);
        {
            int pg = bp * 128 + p0r;
            int yy = (pg >> 5) + dy, xx = (pg & 31) + dx;
            const u16* src = ((unsigned)yy < 32u && (unsigned)xx < 32u)
                ? X2 + (long)(yy * 32 + xx) * K + kc + k0 : zpage;
            gload16(src, &Xs[buf][tid * 8]);
        }
        {
            int pg = bp * 128 + p1r;
            int yy = (pg >> 5) + dy, xx = (pg & 31) + dx;
            const u16* src = ((unsigned)yy < 32u && (unsigned)xx < 32u)
                ? X2 + (long)(yy * 32 + xx) * K + kc + k1 : zpage;
            gload16(src, &Xs[buf][2048 + tid * 8]);
        }
        int rem = mask >> (tt + 1);
        if (rem) tt += __ffs(rem);
        else { tt = __ffs(mask) - 1; kc += 32; }
    };

    STAGE(0);
    __syncthreads();
    int cur = 0;
    for (int i = 0; i < nIt; i++) {
        if (i + 1 < nIt) STAGE(cur ^ 1);
        bf16x8 a = *(const bf16x8*)&Ws[cur][aoff >> 1];
#pragma unroll
        for (int j = 0; j < 8; j++) {
            int boff = (j * 16 + l15) * 64 + quad * 16;
            boff ^= ((boff >> 7) & 3) << 4;
            bf16x8 b = *(const bf16x8*)&Xs[cur][boff >> 1];
            acc[j] = __builtin_amdgcn_mfma_f32_16x16x32_bf16(a, b, acc[j], 0, 0, 0);
        }
        __syncthreads();
        cur ^= 1;
    }

#pragma unroll
    for (int j = 0; j < 8; j++) {
        int pgl = bp * 128 + j * 16 + l15;
        long ob = (long)(bo * 64 + wave * 16 + quad * 4);
#pragma unroll
        for (int r = 0; r < 4; r++)
            atomicAdd(&OUT[(ob + r) * 1024 + pgl], acc[j][r]);
    }
}

// ---------------------------------------------------------------------------
// Old general MFMA conv (kept: rf1/rf2/r2/ap + full fallback path)
// ---------------------------------------------------------------------------
__global__ __launch_bounds__(256) void conv_mfma(
    const void* __restrict__ W, const void* __restrict__ X, float* __restrict__ OUT,
    const int* __restrict__ flag, int x_ext,
    int K, int wrow, int wstride, int woff, int taps, int d, int logIW)
{
    __shared__ __align__(16) u16 Ws[64 * 40];
    __shared__ __align__(16) u16 Xs[128 * 40];

    const int IW = 1 << logIW;
    const int NP = IW * IW;
    const int wf32 = flag[0];
    const int xf32 = x_ext ? wf32 : 1;

    const int tid = threadIdx.x;
    const int bo = blockIdx.x, bp = blockIdx.y;
    const int kcs = K / gridDim.z;
    const int kb = blockIdx.z * kcs;

    const int w_o = tid >> 2, w_kg = (tid & 3) * 8;
    const int x_p = tid >> 1, x_kg = (tid & 1) * 16;
    const int pg  = bp * 128 + x_p;
    const int py  = pg >> logIW, px = pg & (IW - 1);
    const int ty0 = (bp * 128) >> logIW;
    const int ty1 = ty0 + (128 >> logIW) - 1;

    const int wave = tid >> 6, lane = tid & 63;
    const int quad = lane >> 4, l15 = lane & 15;

    f32x4 acc[8];
#pragma unroll
    for (int j = 0; j < 8; j++) {
        f32x4 z = {0.f, 0.f, 0.f, 0.f};
        acc[j] = z;
    }

    const long wbase_o = (long)(bo * 64 + w_o) * wrow + woff;

    for (int kc = kb; kc < kb + kcs; kc += 32) {
        for (int t = 0; t < taps; t++) {
            int dy = 0, dx = 0, wt = 0;
            if (taps == 9) { dy = (t / 3 - 1) * d; dx = (t % 3 - 1) * d; wt = t; }
            if (ty1 + dy < 0 || ty0 + dy >= IW) continue;

            {
                u16 tv[8];
                if (wstride == 1) {
                    long idx = wbase_o + kc + w_kg;
                    if (wf32) {
                        float4 v0 = *(const float4*)((const float*)W + idx);
                        float4 v1 = *(const float4*)((const float*)W + idx + 4);
                        tv[0] = f2bf(v0.x); tv[1] = f2bf(v0.y);
                        tv[2] = f2bf(v0.z); tv[3] = f2bf(v0.w);
                        tv[4] = f2bf(v1.x); tv[5] = f2bf(v1.y);
                        tv[6] = f2bf(v1.z); tv[7] = f2bf(v1.w);
                    } else {
                        ushort4 v0 = *(const ushort4*)((const u16*)W + idx);
                        ushort4 v1 = *(const ushort4*)((const u16*)W + idx + 4);
                        tv[0] = v0.x; tv[1] = v0.y; tv[2] = v0.z; tv[3] = v0.w;
                        tv[4] = v1.x; tv[5] = v1.y; tv[6] = v1.z; tv[7] = v1.w;
                    }
                } else {
                    long idx = wbase_o + wt + (long)(kc + w_kg) * 9;
#pragma unroll
                    for (int i = 0; i < 8; i++)
                        tv[i] = loadbf(W, idx + (long)i * 9, wf32);
                }
                *(ushort4*)&Ws[w_o * 40 + w_kg]     = make_ushort4(tv[0], tv[1], tv[2], tv[3]);
                *(ushort4*)&Ws[w_o * 40 + w_kg + 4] = make_ushort4(tv[4], tv[5], tv[6], tv[7]);
            }
            {
                int yy = py + dy, xv = px + dx;
                bool ok = ((unsigned)yy < (unsigned)IW) && ((unsigned)xv < (unsigned)IW);
                u16 tv[16];
                if (ok) {
                    long idx = (long)(kc + x_kg) * NP + yy * IW + xv;
                    if (xf32) {
#pragma unroll
                        for (int i = 0; i < 16; i++)
                            tv[i] = f2bf(((const float*)X)[idx + (long)i * NP]);
                    } else {
#pragma unroll
                        for (int i = 0; i < 16; i++)
                            tv[i] = ((const u16*)X)[idx + (long)i * NP];
                    }
                } else {
#pragma unroll
                    for (int i = 0; i < 16; i++) tv[i] = 0;
                }
                *(ushort4*)&Xs[x_p * 40 + x_kg]      = make_ushort4(tv[0], tv[1], tv[2], tv[3]);
                *(ushort4*)&Xs[x_p * 40 + x_kg + 4]  = make_ushort4(tv[4], tv[5], tv[6], tv[7]);
                *(ushort4*)&Xs[x_p * 40 + x_kg + 8]  = make_ushort4(tv[8], tv[9], tv[10], tv[11]);
                *(ushort4*)&Xs[x_p * 40 + x_kg + 12] = make_ushort4(tv[12], tv[13], tv[14], tv[15]);
            }
            __syncthreads();
            {
                bf16x8 a = *(const bf16x8*)&Ws[(wave * 16 + l15) * 40 + quad * 8];
#pragma unroll
                for (int j = 0; j < 8; j++) {
                    bf16x8 b = *(const bf16x8*)&Xs[(j * 16 + l15) * 40 + quad * 8];
                    acc[j] = __builtin_amdgcn_mfma_f32_16x16x32_bf16(a, b, acc[j], 0, 0, 0);
                }
            }
            __syncthreads();
        }
    }

#pragma unroll
    for (int j = 0; j < 8; j++) {
        int pgl = bp * 128 + j * 16 + l15;
        long ob = (long)(bo * 64 + wave * 16 + quad * 4);
#pragma unroll
        for (int r = 0; r < 4; r++)
            atomicAdd(&OUT[(ob + r) * NP + pgl], acc[j][r]);
    }
}

// bn+relu in place over (C, N) f32, N = 2^logN
__global__ __launch_bounds__(256) void ep_bnrelu(
    float* __restrict__ buf, const void* __restrict__ s, const void* __restrict__ b,
    const int* __restrict__ flag, int logN, int total)
{
    int f32 = flag[0];
    int g = blockIdx.x * 256 + threadIdx.x;
    if (g >= total) return;
    int c = g >> logN;
    float v = buf[g] * loadv(s, c, f32) + loadv(b, c, f32);
    buf[g] = fmaxf(v, 0.f);
}

__global__ __launch_bounds__(256) void ep_aspp(
    float* __restrict__ buf, const float* __restrict__ f4con,
    const void* __restrict__ s, const void* __restrict__ b, const int* __restrict__ flag)
{
    int f32 = flag[0];
    int g = blockIdx.x * 256 + threadIdx.x;
    int c = g >> 10;
    float v = (buf[g] + f4con[c]) * loadv(s, c, f32) + loadv(b, c, f32);
    buf[g] = fmaxf(v, 0.f);
}

__global__ __launch_bounds__(256) void resize_bn(
    const float* __restrict__ in, float* __restrict__ out,
    const void* __restrict__ s, const void* __restrict__ b,
    const int* __restrict__ flag, int dobn)
{
    int g = blockIdx.x * 256 + threadIdx.x;
    int c = g >> 12, p = g & 4095;
    int oy = p >> 6, ox = p & 63;
    const float r = 31.0f / 63.0f;
    float tyf = oy * r, txf = ox * r;
    int y0 = (int)tyf, x0 = (int)txf;
    float fy = tyf - y0, fx = txf - x0;
    int y1 = y0 + 1 > 31 ? 31 : y0 + 1;
    int x1 = x0 + 1 > 31 ? 31 : x0 + 1;
    const float* pc = in + c * 1024;
    float v00 = pc[y0 * 32 + x0], v01 = pc[y0 * 32 + x1];
    float v10 = pc[y1 * 32 + x0], v11 = pc[y1 * 32 + x1];
    float v = (1.f - fy) * ((1.f - fx) * v00 + fx * v01) +
              fy * ((1.f - fx) * v10 + fx * v11);
    if (dobn) v = fmaxf(v * loadv(s, c, flag[0]) + loadv(b, c, flag[0]), 0.f);
    out[g] = v;
}

__global__ __launch_bounds__(256) void attn_kernel(
    const float* __restrict__ c1r, const float* __restrict__ c2r, float* __restrict__ att)
{
    int tid = threadIdx.x;
    int p = blockIdx.x * 4 + (tid >> 6);
    int lane = tid & 63;
    int y = p >> 6, x = p & 63;
    float a = c1r[lane * 4096 + p];
    float e[9];
#pragma unroll
    for (int ky = 0; ky < 3; ky++)
#pragma unroll
        for (int kx = 0; kx < 3; kx++) {
            int yy = y + 2 * (ky - 1), xx = x + 2 * (kx - 1);
            float v = 0.f;
            if (yy >= 0 && yy < 64 && xx >= 0 && xx < 64)
                v = a * c2r[lane * 4096 + yy * 64 + xx];
#pragma unroll
            for (int off = 32; off; off >>= 1) v += __shfl_xor(v, off);
            e[ky * 3 + kx] = v;
        }
    float m = e[0];
#pragma unroll
    for (int k = 1; k < 9; k++) m = fmaxf(m, e[k]);
    float ssum = 0.f;
#pragma unroll
    for (int k = 0; k < 9; k++) ssum += __expf(e[k] - m);
    if (lane < 9) {
        float mye = e[0];
#pragma unroll
        for (int k = 1; k < 9; k++)
            if (lane == k) mye = e[k];
        att[p * 9 + lane] = __expf(mye - m) / ssum;
    }
}

__global__ __launch_bounds__(256) void gap_kernel(
    const void* __restrict__ x, const int* __restrict__ flag, float* __restrict__ gap)
{
    int f32 = flag[0];
    int tid = threadIdx.x;
    int c = blockIdx.x * 4 + (tid >> 6);
    int lane = tid & 63;
    long base = (long)c * 1024;
    float ssum = 0.f;
#pragma unroll
    for (int i = 0; i < 16; i++) ssum += loadv(x, base + lane + i * 64, f32);
#pragma unroll
    for (int off = 32; off; off >>= 1) ssum += __shfl_xor(ssum, off);
    if (lane == 0) gap[c] = ssum * (1.0f / 1024.0f);
}

__global__ __launch_bounds__(256) void f4_kernel(
    const void* __restrict__ w, const float* __restrict__ gap,
    const void* __restrict__ s, const void* __restrict__ b,
    const int* __restrict__ flag, float* __restrict__ f4c)
{
    int f32 = flag[0];
    int tid = threadIdx.x;
    int o = blockIdx.x * 4 + (tid >> 6);
    int lane = tid & 63;
    long base = (long)o * 4096;
    float ssum = 0.f;
#pragma unroll
    for (int i = 0; i < 64; i++)
        ssum += loadv(w, base + lane + i * 64, f32) * gap[lane + i * 64];
#pragma unroll
    for (int off = 32; off; off >>= 1) ssum += __shfl_xor(ssum, off);
    if (lane == 0) f4c[o] = fmaxf(ssum * loadv(s, o, f32) + loadv(b, o, f32), 0.f);
}

__global__ __launch_bounds__(256) void f4con_kernel(
    const void* __restrict__ ap_w, const float* __restrict__ f4c,
    const int* __restrict__ flag, float* __restrict__ f4con)
{
    int f32 = flag[0];
    int tid = threadIdx.x;
    int o = blockIdx.x * 4 + (tid >> 6);
    int lane = tid & 63;
    long base = (long)o * 2560 + 2048;
    float ssum = 0.f;
#pragma unroll
    for (int i = 0; i < 8; i++)
        ssum += loadv(ap_w, base + lane + i * 64, f32) * f4c[lane + i * 64];
#pragma unroll
    for (int off = 32; off; off >>= 1) ssum += __shfl_xor(ssum, off);
    if (lane == 0) f4con[o] = ssum;
}

__global__ __launch_bounds__(256) void vs_kernel(
    const float* __restrict__ aspp, const void* __restrict__ w,
    const int* __restrict__ flag, float* __restrict__ Vs)
{
    int f32 = flag[0];
    int p = blockIdx.x * 256 + threadIdx.x;
    int q = blockIdx.y;
    long wb = (long)q * 512;
    float a0 = 0.f, a1 = 0.f, a2 = 0.f, a3 = 0.f;
    for (int c = 0; c < 512; c += 4) {
        a0 = fmaf(loadv(w, wb + c + 0, f32), aspp[(c + 0) * 1024 + p], a0);
        a1 = fmaf(loadv(w, wb + c + 1, f32), aspp[(c + 1) * 1024 + p], a1);
        a2 = fmaf(loadv(w, wb + c + 2, f32), aspp[(c + 2) * 1024 + p], a2);
        a3 = fmaf(loadv(w, wb + c + 3, f32), aspp[(c + 3) * 1024 + p], a3);
    }
    Vs[q * 1024 + p] = (a0 + a1) + (a2 + a3);
}

__global__ __launch_bounds__(256) void final_kernel(
    const float* __restrict__ att, const float* __restrict__ V,
    const void* __restrict__ bias, const int* __restrict__ flag, void* __restrict__ out)
{
    int f32 = flag[0];
    int g = blockIdx.x * 256 + threadIdx.x;
    int q = g >> 12, p = g & 4095;
    int y = p >> 6, x = p & 63;
    const float* a = att + p * 9;
    const float* v = V + q * 4096;
    float acc = loadv(bias, q, f32);
#pragma unroll
    for (int ky = 0; ky < 3; ky++)
#pragma unroll
        for (int kx = 0; kx < 3; kx++) {
            int yy = y + 2 * (ky - 1), xx = x + 2 * (kx - 1);
            if (yy >= 0 && yy < 64 && xx >= 0 && xx < 64)
                acc += a[ky * 3 + kx] * v[yy * 64 + xx];
        }
    if (f32) ((float*)out)[g] = acc;
    else     ((__hip_bfloat16*)out)[g] = __float2bfloat16(acc);
}

// ---------------------------------------------------------------------------
// Host orchestration
// ---------------------------------------------------------------------------
extern "C" void kernel_launch(void* const* d_in, const int* in_sizes, int n_in,
                              void* d_out, int out_size, void* d_ws, size_t ws_size,
                              hipStream_t stream)
{
    const void* c1    = d_in[0];
    const void* c2    = d_in[1];
    const void* x     = d_in[2];
    const void* rf1_w = d_in[3];
    const void* rf1_s = d_in[4];
    const void* rf1_b = d_in[5];
    const void* rf2_w = d_in[6];
    const void* rf2_s = d_in[7];
    const void* rf2_b = d_in[8];
    const void* r2_w  = d_in[9];
    const void* r2_s  = d_in[10];
    const void* r2_b  = d_in[11];
    const void* a0_w  = d_in[12];
    const void* a0_s  = d_in[13];
    const void* a0_b  = d_in[14];
    const void* a1_w  = d_in[15];
    const void* a1_s  = d_in[16];
    const void* a1_b  = d_in[17];
    const void* a2_w  = d_in[18];
    const void* a2_s  = d_in[19];
    const void* a2_b  = d_in[20];
    const void* a3_w  = d_in[21];
    const void* a3_s  = d_in[22];
    const void* a3_b  = d_in[23];
    const void* a4_w  = d_in[24];
    const void* a4_s  = d_in[25];
    const void* a4_b  = d_in[26];
    const void* ap_w  = d_in[27];
    const void* ap_s  = d_in[28];
    const void* ap_b  = d_in[29];
    const void* c6_w  = d_in[30];
    const void* c6_b  = d_in[31];

    // ---- workspace layout (float slots) ----
    const long F_BUFR = 0;          //  262144  rf1 out [accum]
    const long F_C1R  = 262144;     //  262144  rf2 out [accum]
    const long F_BUFC = 524288;     //   65536  r2 out  [accum]
    const long F_ASPP = 589824;     //  524288  ap out  [accum]
    const long F_ZP   = 1114112;    //     256  zero page (stays zero)
    const long F_TMP  = 1114368;    //  524288  ASPP branch [accum, reused x4]
    const long F_C2R  = 1638656;    //  262144
    const long F_ATT  = 1900800;    //   36864
    const long F_GAPV = 1937664;    //    4096
    const long F_F4C  = 1941760;    //     512
    const long F_F4CO = 1942272;    //     512
    const long F_VS   = 1942784;    //   19456
    const long F_V    = 1962240;    //   77824
    const long F_FLAG = 2040064;    //      64 (int flag + pad)
    const long F_X2   = 2040128;    // 2097152 float-slots (1024x4096 bf16)
    const long F_W2   = 4137280;    // 9437184 float-slots (9x512x4096 bf16)
    const long F_W1   = 13574464;   // 1048576 float-slots (512x4096 bf16)
    const long F_END  = 14623040;

    float* ws    = (float*)d_ws;
    float* bufR  = ws + F_BUFR;
    float* c1r   = ws + F_C1R;
    float* bufC  = ws + F_BUFC;
    float* aspp  = ws + F_ASPP;
    float* tmp   = ws + F_TMP;
    float* c2r   = ws + F_C2R;
    float* att   = ws + F_ATT;
    float* gapv  = ws + F_GAPV;
    float* f4c   = ws + F_F4C;
    float* f4con = ws + F_F4CO;
    float* Vs    = ws + F_VS;
    float* V     = ws + F_V;
    int*   flag  = (int*)(ws + F_FLAG);
    u16*   X2u   = (u16*)(ws + F_X2);
    u16*   W2u   = (u16*)(ws + F_W2);
    u16*   W1u   = (u16*)(ws + F_W1);
    const u16* zp16 = (const u16*)(ws + F_ZP);

    const bool big = ws_size >= (size_t)F_END * 4;

    // ---- dtype probe + zero accumulators (bufR..aspp + zero page) ----
    detect_kernel<<<1, 256, 0, stream>>>((const u16*)c1, flag);
    zero_kernel<<<1024, 256, 0, stream>>>(ws, 1114368);

    // ---- refine(c1): two 3x3 dil-2 convs + bn_relu (IW=64, P=4096) ----
    conv_mfma<<<dim3(1, 32, 4), 256, 0, stream>>>(rf1_w, c1, bufR, flag, 1,
                                                  256, 256 * 9, 9, 0, 9, 2, 6);
    ep_bnrelu<<<1024, 256, 0, stream>>>(bufR, rf1_s, rf1_b, flag, 12, 262144);
    conv_mfma<<<dim3(1, 32, 2), 256, 0, stream>>>(rf2_w, bufR, c1r, flag, 0,
                                                  64, 64 * 9, 9, 0, 9, 2, 6);
    ep_bnrelu<<<1024, 256, 0, stream>>>(c1r, rf2_s, rf2_b, flag, 12, 262144);

    // ---- refine2: 1x1 conv on c2, then resize+bn ----
    conv_mfma<<<dim3(1, 8, 4), 256, 0, stream>>>(r2_w, c2, bufC, flag, 1,
                                                 512, 512, 1, 0, 1, 0, 5);
    resize_bn<<<1024, 256, 0, stream>>>(bufC, c2r, r2_s, r2_b, flag, 1);

    // ---- attention ----
    attn_kernel<<<1024, 256, 0, stream>>>(c1r, c2r, att);

    // ---- GAP branch ----
    gap_kernel<<<1024, 256, 0, stream>>>(x, flag, gapv);
    f4_kernel<<<128, 256, 0, stream>>>(a4_w, gapv, a4_s, a4_b, flag, f4c);
    f4con_kernel<<<128, 256, 0, stream>>>(ap_w, f4c, flag, f4con);

    // ---- one-time repack of x for the fast conv path ----
    if (big)
        xpose_x<<<dim3(16, 64), 256, 0, stream>>>(x, X2u, flag);

    // ---- ASPP seg0: 1x1 ----
    zero_kernel<<<512, 256, 0, stream>>>(tmp, 524288);
    if (big) {
        xform_w1<<<8192, 256, 0, stream>>>(a0_w, W1u, flag, 4096, 0, 1);
        conv_gemm<<<dim3(8, 8, 8), 256, 0, stream>>>(W1u, X2u, zp16, tmp,
                                                     4096, 512, 1, 0);
    } else {
        conv_mfma<<<dim3(8, 8, 4), 256, 0, stream>>>(a0_w, x, tmp, flag, 1,
                                                     4096, 4096, 1, 0, 1, 0, 5);
    }
    ep_bnrelu<<<2048, 256, 0, stream>>>(tmp, a0_s, a0_b, flag, 10, 524288);
    conv_mfma<<<dim3(8, 8, 2), 256, 0, stream>>>(ap_w, tmp, aspp, flag, 0,
                                                 512, 2560, 1, 0, 1, 0, 5);
    // ---- seg1: 3x3 d=12 ----
    zero_kernel<<<512, 256, 0, stream>>>(tmp, 524288);
    if (big) {
        xform_w9<<<dim3(16, 512), 256, 0, stream>>>(a1_w, W2u, flag);
        conv_gemm<<<dim3(8, 8, 16), 256, 0, stream>>>(W2u, X2u, zp16, tmp,
                                                      4096, 512, 9, 12);
    } else {
        conv_mfma<<<dim3(8, 8, 8), 256, 0, stream>>>(a1_w, x, tmp, flag, 1,
                                                     4096, 4096 * 9, 9, 0, 9, 12, 5);
    }
    ep_bnrelu<<<2048, 256, 0, stream>>>(tmp, a1_s, a1_b, flag, 10, 524288);
    conv_mfma<<<dim3(8, 8, 2), 256, 0, stream>>>(ap_w, tmp, aspp, flag, 0,
                                                 512, 2560, 1, 512, 1, 0, 5);
    // ---- seg2: 3x3 d=24 ----
    zero_kernel<<<512, 256, 0, stream>>>(tmp, 524288);
    if (big) {
        xform_w9<<<dim3(16, 512), 256, 0, stream>>>(a2_w, W2u, flag);
        conv_gemm<<<dim3(8, 8, 16), 256, 0, stream>>>(W2u, X2u, zp16, tmp,
                                                      4096, 512, 9, 24);
    } else {
        conv_mfma<<<dim3(8, 8, 8), 256, 0, stream>>>(a2_w, x, tmp, flag, 1,
                                                     4096, 4096 * 9, 9, 0, 9, 24, 5);
    }
    ep_bnrelu<<<2048, 256, 0, stream>>>(tmp, a2_s, a2_b, flag, 10, 524288);
    conv_mfma<<<dim3(8, 8, 2), 256, 0, stream>>>(ap_w, tmp, aspp, flag, 0,
                                                 512, 2560, 1, 1024, 1, 0, 5);
    // ---- seg3: 3x3 d=36 -> center tap only ----
    zero_kernel<<<512, 256, 0, stream>>>(tmp, 524288);
    if (big) {
        xform_w1<<<8192, 256, 0, stream>>>(a3_w, W1u, flag, 36864, 4, 9);
        conv_gemm<<<dim3(8, 8, 8), 256, 0, stream>>>(W1u, X2u, zp16, tmp,
                                                     4096, 512, 1, 0);
    } else {
        conv_mfma<<<dim3(8, 8, 4), 256, 0, stream>>>(a3_w, x, tmp, flag, 1,
                                                     4096, 4096 * 9, 9, 4, 1, 0, 5);
    }
    ep_bnrelu<<<2048, 256, 0, stream>>>(tmp, a3_s, a3_b, flag, 10, 524288);
    conv_mfma<<<dim3(8, 8, 2), 256, 0, stream>>>(ap_w, tmp, aspp, flag, 0,
                                                 512, 2560, 1, 1536, 1, 0, 5);
    // ---- ASPP epilogue ----
    ep_aspp<<<2048, 256, 0, stream>>>(aspp, f4con, ap_s, ap_b, flag);

    // ---- tail ----
    vs_kernel<<<dim3(4, 19), 256, 0, stream>>>(aspp, c6_w, flag, Vs);
    resize_bn<<<304, 256, 0, stream>>>(Vs, V, nullptr, nullptr, flag, 0);
    final_kernel<<<304, 256, 0, stream>>>(att, V, c6_b, flag, d_out);
}

// Round 2
// 731.477 us; speedup vs baseline: 2.3057x; 1.0777x over previous
//
#include <hip/hip_runtime.h>
#include <hip/hip_bf16.h>

// ---------------------------------------------------------------------------
// up_deeplabv3Head — round 5: all convs on the repacked GEMM engine.
// conv_gemm templated on MF (o-tile 64 or 128), XCD-aware block swizzle,
// generic transpose(+bn_relu) repack to [p][c] bf16, generic weight repacks.
// Old conv_mfma engine kept only for the small-workspace fallback path.
// ---------------------------------------------------------------------------

typedef unsigned short u16;
typedef short bf16x8 __attribute__((ext_vector_type(8)));
typedef float f32x4  __attribute__((ext_vector_type(4)));
typedef u16   u16x8  __attribute__((ext_vector_type(8)));

__device__ __forceinline__ float bf2f(u16 u) {
    return __uint_as_float(((unsigned int)u) << 16);
}
__device__ __forceinline__ u16 f2bf(float f) {   // round-to-nearest-even
    unsigned u = __float_as_uint(f);
    return (u16)((u + 0x7FFFu + ((u >> 16) & 1u)) >> 16);
}
// flag f32: 1 -> storage fp32, 0 -> storage bf16
__device__ __forceinline__ float loadv(const void* p, long i, int f32) {
    return f32 ? ((const float*)p)[i] : bf2f(((const u16*)p)[i]);
}
__device__ __forceinline__ u16 loadbf(const void* p, long i, int f32) {
    return f32 ? f2bf(((const float*)p)[i]) : ((const u16*)p)[i];
}

__device__ __forceinline__ void gload16(const u16* g, u16* l) {
    __builtin_amdgcn_global_load_lds(
        (const __attribute__((address_space(1))) unsigned int*)(g),
        (__attribute__((address_space(3))) unsigned int*)(l), 16, 0, 0);
}

// ---------------------------------------------------------------------------
// dtype probe (verified): bf16-stored N(0,1) has ~0 large-exponent words.
// ---------------------------------------------------------------------------
__global__ __launch_bounds__(256) void detect_kernel(
    const u16* __restrict__ c1, int* __restrict__ flag)
{
    __shared__ int cnt;
    if (threadIdx.x == 0) cnt = 0;
    __syncthreads();
    int local = 0;
    for (int i = threadIdx.x; i < 16384; i += 256) {
        u16 u = c1[i];
        if ((u & 0x7F80) >= 0x4F00) local++;
    }
    atomicAdd(&cnt, local);
    __syncthreads();
    if (threadIdx.x == 0) flag[0] = (cnt > 256) ? 1 : 0;
}

__global__ __launch_bounds__(256) void zero_kernel(float* __restrict__ p, int n)
{
    for (int g = blockIdx.x * 256 + threadIdx.x; g < n; g += gridDim.x * 256)
        p[g] = 0.f;
}

// ---------------------------------------------------------------------------
// Generic repack kernels
// ---------------------------------------------------------------------------

// src [C][P] (f32 if !flagged, else flag-dtype) -> dst [P][C] bf16.
// Optional fused bn+relu per channel c (only used on f32 sources).
// Grid (P/64, C/64). C, P powers of two, C >= 64, P >= 64.
__global__ __launch_bounds__(256) void xpose_bn(
    const void* __restrict__ src, u16* __restrict__ dst,
    const void* __restrict__ s, const void* __restrict__ b,
    const int* __restrict__ flag, int flagged, int dobn, int C, int P)
{
    __shared__ u16 T[64][72];
    const int fl = flag[0];
    const int srcf32 = flagged ? fl : 1;
    const int p0 = blockIdx.x * 64, c0 = blockIdx.y * 64;
    const int t = threadIdx.x;
    {
        int c = t >> 2, pq = (t & 3) * 16;
        float sc = 1.f, bc = 0.f;
        if (dobn) { sc = loadv(s, c0 + c, fl); bc = loadv(b, c0 + c, fl); }
        const long sb = (long)(c0 + c) * P + p0 + pq;
        if (srcf32) {
            const float* sp = (const float*)src + sb;
#pragma unroll
            for (int i = 0; i < 16; i += 4) {
                float4 v = *(const float4*)(sp + i);
                float vv[4] = {v.x, v.y, v.z, v.w};
#pragma unroll
                for (int j = 0; j < 4; j++) {
                    float u = vv[j];
                    if (dobn) u = fmaxf(u * sc + bc, 0.f);
                    T[pq + i + j][c] = f2bf(u);
                }
            }
        } else {
            const u16* sp = (const u16*)src + sb;
#pragma unroll
            for (int i = 0; i < 16; i++) T[pq + i][c] = sp[i];
        }
    }
    __syncthreads();
    {
        int p = t >> 2, cq = (t & 3) * 16;
        u16x8 v0, v1;
#pragma unroll
        for (int i = 0; i < 8; i++) { v0[i] = T[p][cq + i]; v1[i] = T[p][cq + 8 + i]; }
        *(u16x8*)&dst[(long)(p0 + p) * C + c0 + cq] = v0;
        *(u16x8*)&dst[(long)(p0 + p) * C + c0 + cq + 8] = v1;
    }
}

// w [O][C][9] -> W9 [9][O][C] bf16. Grid (ceil(C/256), O).
__global__ __launch_bounds__(256) void xform_w9(
    const void* __restrict__ w, u16* __restrict__ W9, const int* __restrict__ flag,
    int O, int C)
{
    const int f32 = flag[0];
    const int o = blockIdx.y;
    const int c = blockIdx.x * 256 + threadIdx.x;
    if (c >= C) return;
    const long src = ((long)o * C + c) * 9;
    u16 v[9];
    if (f32) {
        const float* p = (const float*)w + src;
#pragma unroll
        for (int j = 0; j < 9; j++) v[j] = f2bf(p[j]);
    } else {
        const u16* p = (const u16*)w + src;
#pragma unroll
        for (int j = 0; j < 9; j++) v[j] = p[j];
    }
#pragma unroll
    for (int j = 0; j < 9; j++)
        W9[(long)j * O * C + (long)o * C + c] = v[j];
}

// generic 1-plane extract: Wo[o*C + c] = w[o*ldi + off + c*st] as bf16.
// Grid O*C/256, C = 1<<logC.
__global__ __launch_bounds__(256) void xform_w1(
    const void* __restrict__ w, u16* __restrict__ Wo, const int* __restrict__ flag,
    int ldi, int off, int st, int logC)
{
    const int f32 = flag[0];
    long g = (long)blockIdx.x * 256 + threadIdx.x;
    long o = g >> logC;
    int c = (int)(g & ((1 << logC) - 1));
    Wo[g] = loadbf(w, o * ldi + off + (long)c * st, f32);
}

// ---------------------------------------------------------------------------
// conv_gemm<MF>: OUT[o,p] += sum_{t in mask, c} W2[t][o][c] * X2[p+shift(t)][c]
// Tile: (MF*64) o x 128 px, 4 waves, MF m-frags x 8 n-frags per wave.
// Double-buffered LDS, global_load_lds staging, XOR swizzle
// byte ^= ((byte>>7)&3)<<4 (involution, row-preserving). 1-D grid with
// XCD-aware decode: all nbp blocks of a (bo,bz) group land on one XCD
// (requires nb%8==0 && (nbo*nz)%8==0 when swz=1).
// Split-K (kcs per block), fp32 atomicAdd into pre-zeroed OUT.
// ---------------------------------------------------------------------------
template<int MF>
__global__ __launch_bounds__(256, 4) void conv_gemm(
    const u16* __restrict__ W2, const u16* __restrict__ X2,
    const u16* __restrict__ zpage, float* __restrict__ OUT,
    int K, int O, int taps, int d, int logIW, int P,
    int nbo, int nbp, int kcs, int swz)
{
    __shared__ __align__(16) u16 Ws[2][MF * 2048];
    __shared__ __align__(16) u16 Xs[2][4096];

    const int tid = threadIdx.x;
    int bo, bp, bz;
    {
        int pid = blockIdx.x;
        if (swz) {
            int xcd = pid & 7, j = pid >> 3;
            bp = j % nbp;
            int g = j / nbp;
            int G = xcd + 8 * g;
            bo = G % nbo; bz = G / nbo;
        } else {
            bp = pid % nbp;
            int q = pid / nbp;
            bo = q % nbo; bz = q / nbo;
        }
    }
    const int kb = bz * kcs;
    const int IW = 1 << logIW;

    const int wave = tid >> 6, lane = tid & 63;
    const int quad = lane >> 4, l15 = lane & 15;

    // uniform valid-tap mask over this tile's row band
    int mask = 1;
    if (taps == 9) {
        const int rb = 128 >> logIW;
        const int ty0 = bp * rb;
        mask = 0;
        for (int t = 0; t < 9; t++) {
            int dy = (t / 3 - 1) * d;
            if (ty0 + rb - 1 + dy >= 0 && ty0 + dy < IW) mask |= (1 << t);
        }
    }
    const int nIt = (kcs >> 5) * __popc(mask);

    // per-thread staging decode: physical dest byte b holds logical l
    int wrow[MF], wk[MF];
#pragma unroll
    for (int li = 0; li < MF; li++) {
        int bb = li * 4096 + tid * 16;
        int l = bb ^ (((bb >> 7) & 3) << 4);
        wrow[li] = l >> 6; wk[li] = ((l >> 4) & 3) * 8;
    }
    int xrow[2], xk[2];
#pragma unroll
    for (int li = 0; li < 2; li++) {
        int bb = li * 4096 + tid * 16;
        int l = bb ^ (((bb >> 7) & 3) << 4);
        xrow[li] = l >> 6; xk[li] = ((l >> 4) & 3) * 8;
    }

    const long wplane = (long)O * K;

    f32x4 acc[MF][8];
#pragma unroll
    for (int mi = 0; mi < MF; mi++)
#pragma unroll
        for (int j = 0; j < 8; j++) {
            f32x4 z = {0.f, 0.f, 0.f, 0.f};
            acc[mi][j] = z;
        }

    int arow[MF];
#pragma unroll
    for (int mi = 0; mi < MF; mi++) {
        int ao = (wave * (MF * 16) + mi * 16 + l15) * 64 + quad * 16;
        arow[mi] = ao ^ (((ao >> 7) & 3) << 4);
    }

    int tt = __ffs(mask) - 1;
    int kc = kb;

    auto STAGE = [&](int buf) {
        int dy = 0, dx = 0;
        if (taps == 9) { dy = (tt / 3 - 1) * d; dx = (tt % 3 - 1) * d; }
#pragma unroll
        for (int li = 0; li < MF; li++)
            gload16(W2 + (long)tt * wplane + (long)(bo * (MF * 64) + wrow[li]) * K + kc + wk[li],
                    &Ws[buf][li * 2048 + tid * 8]);
#pragma unroll
        for (int li = 0; li < 2; li++) {
            int pg = bp * 128 + xrow[li];
            const u16* src;
            if (taps == 9) {
                int yy = (pg >> logIW) + dy, xx = (pg & (IW - 1)) + dx;
                src = ((unsigned)yy < (unsigned)IW && (unsigned)xx < (unsigned)IW)
                    ? X2 + (long)((yy << logIW) | xx) * K + kc + xk[li] : zpage;
            } else {
                src = X2 + (long)pg * K + kc + xk[li];
            }
            gload16(src, &Xs[buf][li * 2048 + tid * 8]);
        }
        int rem = mask >> (tt + 1);
        if (rem) tt += __ffs(rem);
        else { tt = __ffs(mask) - 1; kc += 32; }
    };

    STAGE(0);
    __syncthreads();
    int cur = 0;
    for (int i = 0; i < nIt; i++) {
        if (i + 1 < nIt) STAGE(cur ^ 1);
        bf16x8 a[MF];
#pragma unroll
        for (int mi = 0; mi < MF; mi++)
            a[mi] = *(const bf16x8*)&Ws[cur][arow[mi] >> 1];
#pragma unroll
        for (int j = 0; j < 8; j++) {
            int boff = (j * 16 + l15) * 64 + quad * 16;
            boff ^= ((boff >> 7) & 3) << 4;
            bf16x8 b = *(const bf16x8*)&Xs[cur][boff >> 1];
#pragma unroll
            for (int mi = 0; mi < MF; mi++)
                acc[mi][j] = __builtin_amdgcn_mfma_f32_16x16x32_bf16(a[mi], b, acc[mi][j], 0, 0, 0);
        }
        __syncthreads();
        cur ^= 1;
    }

#pragma unroll
    for (int mi = 0; mi < MF; mi++)
#pragma unroll
        for (int j = 0; j < 8; j++) {
            int pgl = bp * 128 + j * 16 + l15;
            long ob = (long)(bo * (MF * 64) + wave * (MF * 16) + mi * 16 + quad * 4);
#pragma unroll
            for (int r = 0; r < 4; r++)
                atomicAdd(&OUT[(ob + r) * P + pgl], acc[mi][j][r]);
        }
}

// ---------------------------------------------------------------------------
// Old general MFMA conv (small-workspace fallback path only)
// ---------------------------------------------------------------------------
__global__ __launch_bounds__(256) void conv_mfma(
    const void* __restrict__ W, const void* __restrict__ X, float* __restrict__ OUT,
    const int* __restrict__ flag, int x_ext,
    int K, int wrow, int wstride, int woff, int taps, int d, int logIW)
{
    __shared__ __align__(16) u16 Ws[64 * 40];
    __shared__ __align__(16) u16 Xs[128 * 40];

    const int IW = 1 << logIW;
    const int NP = IW * IW;
    const int wf32 = flag[0];
    const int xf32 = x_ext ? wf32 : 1;

    const int tid = threadIdx.x;
    const int bo = blockIdx.x, bp = blockIdx.y;
    const int kcs = K / gridDim.z;
    const int kb = blockIdx.z * kcs;

    const int w_o = tid >> 2, w_kg = (tid & 3) * 8;
    const int x_p = tid >> 1, x_kg = (tid & 1) * 16;
    const int pg  = bp * 128 + x_p;
    const int py  = pg >> logIW, px = pg & (IW - 1);
    const int ty0 = (bp * 128) >> logIW;
    const int ty1 = ty0 + (128 >> logIW) - 1;

    const int wave = tid >> 6, lane = tid & 63;
    const int quad = lane >> 4, l15 = lane & 15;

    f32x4 acc[8];
#pragma unroll
    for (int j = 0; j < 8; j++) {
        f32x4 z = {0.f, 0.f, 0.f, 0.f};
        acc[j] = z;
    }

    const long wbase_o = (long)(bo * 64 + w_o) * wrow + woff;

    for (int kc = kb; kc < kb + kcs; kc += 32) {
        for (int t = 0; t < taps; t++) {
            int dy = 0, dx = 0, wt = 0;
            if (taps == 9) { dy = (t / 3 - 1) * d; dx = (t % 3 - 1) * d; wt = t; }
            if (ty1 + dy < 0 || ty0 + dy >= IW) continue;

            {
                u16 tv[8];
                if (wstride == 1) {
                    long idx = wbase_o + kc + w_kg;
                    if (wf32) {
                        float4 v0 = *(const float4*)((const float*)W + idx);
                        float4 v1 = *(const float4*)((const float*)W + idx + 4);
                        tv[0] = f2bf(v0.x); tv[1] = f2bf(v0.y);
                        tv[2] = f2bf(v0.z); tv[3] = f2bf(v0.w);
                        tv[4] = f2bf(v1.x); tv[5] = f2bf(v1.y);
                        tv[6] = f2bf(v1.z); tv[7] = f2bf(v1.w);
                    } else {
                        ushort4 v0 = *(const ushort4*)((const u16*)W + idx);
                        ushort4 v1 = *(const ushort4*)((const u16*)W + idx + 4);
                        tv[0] = v0.x; tv[1] = v0.y; tv[2] = v0.z; tv[3] = v0.w;
                        tv[4] = v1.x; tv[5] = v1.y; tv[6] = v1.z; tv[7] = v1.w;
                    }
                } else {
                    long idx = wbase_o + wt + (long)(kc + w_kg) * 9;
#pragma unroll
                    for (int i = 0; i < 8; i++)
                        tv[i] = loadbf(W, idx + (long)i * 9, wf32);
                }
                *(ushort4*)&Ws[w_o * 40 + w_kg]     = make_ushort4(tv[0], tv[1], tv[2], tv[3]);
                *(ushort4*)&Ws[w_o * 40 + w_kg + 4] = make_ushort4(tv[4], tv[5], tv[6], tv[7]);
            }
            {
                int yy = py + dy, xv = px + dx;
                bool ok = ((unsigned)yy < (unsigned)IW) && ((unsigned)xv < (unsigned)IW);
                u16 tv[16];
                if (ok) {
                    long idx = (long)(kc + x_kg) * NP + yy * IW + xv;
                    if (xf32) {
#pragma unroll
                        for (int i = 0; i < 16; i++)
                            tv[i] = f2bf(((const float*)X)[idx + (long)i * NP]);
                    } else {
#pragma unroll
                        for (int i = 0; i < 16; i++)
                            tv[i] = ((const u16*)X)[idx + (long)i * NP];
                    }
                } else {
#pragma unroll
                    for (int i = 0; i < 16; i++) tv[i] = 0;
                }
                *(ushort4*)&Xs[x_p * 40 + x_kg]      = make_ushort4(tv[0], tv[1], tv[2], tv[3]);
                *(ushort4*)&Xs[x_p * 40 + x_kg + 4]  = make_ushort4(tv[4], tv[5], tv[6], tv[7]);
                *(ushort4*)&Xs[x_p * 40 + x_kg + 8]  = make_ushort4(tv[8], tv[9], tv[10], tv[11]);
                *(ushort4*)&Xs[x_p * 40 + x_kg + 12] = make_ushort4(tv[12], tv[13], tv[14], tv[15]);
            }
            __syncthreads();
            {
                bf16x8 a = *(const bf16x8*)&Ws[(wave * 16 + l15) * 40 + quad * 8];
#pragma unroll
                for (int j = 0; j < 8; j++) {
                    bf16x8 b = *(const bf16x8*)&Xs[(j * 16 + l15) * 40 + quad * 8];
                    acc[j] = __builtin_amdgcn_mfma_f32_16x16x32_bf16(a, b, acc[j], 0, 0, 0);
                }
            }
            __syncthreads();
        }
    }

#pragma unroll
    for (int j = 0; j < 8; j++) {
        int pgl = bp * 128 + j * 16 + l15;
        long ob = (long)(bo * 64 + wave * 16 + quad * 4);
#pragma unroll
        for (int r = 0; r < 4; r++)
            atomicAdd(&OUT[(ob + r) * NP + pgl], acc[j][r]);
    }
}

// bn+relu in place over (C, N) f32, N = 2^logN
__global__ __launch_bounds__(256) void ep_bnrelu(
    float* __restrict__ buf, const void* __restrict__ s, const void* __restrict__ b,
    const int* __restrict__ flag, int logN, int total)
{
    int f32 = flag[0];
    int g = blockIdx.x * 256 + threadIdx.x;
    if (g >= total) return;
    int c = g >> logN;
    float v = buf[g] * loadv(s, c, f32) + loadv(b, c, f32);
    buf[g] = fmaxf(v, 0.f);
}

__global__ __launch_bounds__(256) void ep_aspp(
    float* __restrict__ buf, const float* __restrict__ f4con,
    const void* __restrict__ s, const void* __restrict__ b, const int* __restrict__ flag)
{
    int f32 = flag[0];
    int g = blockIdx.x * 256 + threadIdx.x;
    int c = g >> 10;
    float v = (buf[g] + f4con[c]) * loadv(s, c, f32) + loadv(b, c, f32);
    buf[g] = fmaxf(v, 0.f);
}

__global__ __launch_bounds__(256) void resize_bn(
    const float* __restrict__ in, float* __restrict__ out,
    const void* __restrict__ s, const void* __restrict__ b,
    const int* __restrict__ flag, int dobn)
{
    int g = blockIdx.x * 256 + threadIdx.x;
    int c = g >> 12, p = g & 4095;
    int oy = p >> 6, ox = p & 63;
    const float r = 31.0f / 63.0f;
    float tyf = oy * r, txf = ox * r;
    int y0 = (int)tyf, x0 = (int)txf;
    float fy = tyf - y0, fx = txf - x0;
    int y1 = y0 + 1 > 31 ? 31 : y0 + 1;
    int x1 = x0 + 1 > 31 ? 31 : x0 + 1;
    const float* pc = in + c * 1024;
    float v00 = pc[y0 * 32 + x0], v01 = pc[y0 * 32 + x1];
    float v10 = pc[y1 * 32 + x0], v11 = pc[y1 * 32 + x1];
    float v = (1.f - fy) * ((1.f - fx) * v00 + fx * v01) +
              fy * ((1.f - fx) * v10 + fx * v11);
    if (dobn) v = fmaxf(v * loadv(s, c, flag[0]) + loadv(b, c, flag[0]), 0.f);
    out[g] = v;
}

__global__ __launch_bounds__(256) void attn_kernel(
    const float* __restrict__ c1r, const float* __restrict__ c2r, float* __restrict__ att)
{
    int tid = threadIdx.x;
    int p = blockIdx.x * 4 + (tid >> 6);
    int lane = tid & 63;
    int y = p >> 6, x = p & 63;
    float a = c1r[lane * 4096 + p];
    float e[9];
#pragma unroll
    for (int ky = 0; ky < 3; ky++)
#pragma unroll
        for (int kx = 0; kx < 3; kx++) {
            int yy = y + 2 * (ky - 1), xx = x + 2 * (kx - 1);
            float v = 0.f;
            if (yy >= 0 && yy < 64 && xx >= 0 && xx < 64)
                v = a * c2r[lane * 4096 + yy * 64 + xx];
#pragma unroll
            for (int off = 32; off; off >>= 1) v += __shfl_xor(v, off);
            e[ky * 3 + kx] = v;
        }
    float m = e[0];
#pragma unroll
    for (int k = 1; k < 9; k++) m = fmaxf(m, e[k]);
    float ssum = 0.f;
#pragma unroll
    for (int k = 0; k < 9; k++) ssum += __expf(e[k] - m);
    if (lane < 9) {
        float mye = e[0];
#pragma unroll
        for (int k = 1; k < 9; k++)
            if (lane == k) mye = e[k];
        att[p * 9 + lane] = __expf(mye - m) / ssum;
    }
}

__global__ __launch_bounds__(256) void gap_kernel(
    const void* __restrict__ x, const int* __restrict__ flag, float* __restrict__ gap)
{
    int f32 = flag[0];
    int tid = threadIdx.x;
    int c = blockIdx.x * 4 + (tid >> 6);
    int lane = tid & 63;
    long base = (long)c * 1024;
    float ssum = 0.f;
#pragma unroll
    for (int i = 0; i < 16; i++) ssum += loadv(x, base + lane + i * 64, f32);
#pragma unroll
    for (int off = 32; off; off >>= 1) ssum += __shfl_xor(ssum, off);
    if (lane == 0) gap[c] = ssum * (1.0f / 1024.0f);
}

__global__ __launch_bounds__(256) void f4_kernel(
    const void* __restrict__ w, const float* __restrict__ gap,
    const void* __restrict__ s, const void* __restrict__ b,
    const int* __restrict__ flag, float* __restrict__ f4c)
{
    int f32 = flag[0];
    int tid = threadIdx.x;
    int o = blockIdx.x * 4 + (tid >> 6);
    int lane = tid & 63;
    long base = (long)o * 4096;
    float ssum = 0.f;
#pragma unroll
    for (int i = 0; i < 64; i++)
        ssum += loadv(w, base + lane + i * 64, f32) * gap[lane + i * 64];
#pragma unroll
    for (int off = 32; off; off >>= 1) ssum += __shfl_xor(ssum, off);
    if (lane == 0) f4c[o] = fmaxf(ssum * loadv(s, o, f32) + loadv(b, o, f32), 0.f);
}

__global__ __launch_bounds__(256) void f4con_kernel(
    const void* __restrict__ ap_w, const float* __restrict__ f4c,
    const int* __restrict__ flag, float* __restrict__ f4con)
{
    int f32 = flag[0];
    int tid = threadIdx.x;
    int o = blockIdx.x * 4 + (tid >> 6);
    int lane = tid & 63;
    long base = (long)o * 2560 + 2048;
    float ssum = 0.f;
#pragma unroll
    for (int i = 0; i < 8; i++)
        ssum += loadv(ap_w, base + lane + i * 64, f32) * f4c[lane + i * 64];
#pragma unroll
    for (int off = 32; off; off >>= 1) ssum += __shfl_xor(ssum, off);
    if (lane == 0) f4con[o] = ssum;
}

__global__ __launch_bounds__(256) void vs_kernel(
    const float* __restrict__ aspp, const void* __restrict__ w,
    const int* __restrict__ flag, float* __restrict__ Vs)
{
    int f32 = flag[0];
    int p = blockIdx.x * 256 + threadIdx.x;
    int q = blockIdx.y;
    long wb = (long)q * 512;
    float a0 = 0.f, a1 = 0.f, a2 = 0.f, a3 = 0.f;
    for (int c = 0; c < 512; c += 4) {
        a0 = fmaf(loadv(w, wb + c + 0, f32), aspp[(c + 0) * 1024 + p], a0);
        a1 = fmaf(loadv(w, wb + c + 1, f32), aspp[(c + 1) * 1024 + p], a1);
        a2 = fmaf(loadv(w, wb + c + 2, f32), aspp[(c + 2) * 1024 + p], a2);
        a3 = fmaf(loadv(w, wb + c + 3, f32), aspp[(c + 3) * 1024 + p], a3);
    }
    Vs[q * 1024 + p] = (a0 + a1) + (a2 + a3);
}

__global__ __launch_bounds__(256) void final_kernel(
    const float* __restrict__ att, const float* __restrict__ V,
    const void* __restrict__ bias, const int* __restrict__ flag, void* __restrict__ out)
{
    int f32 = flag[0];
    int g = blockIdx.x * 256 + threadIdx.x;
    int q = g >> 12, p = g & 4095;
    int y = p >> 6, x = p & 63;
    const float* a = att + p * 9;
    const float* v = V + q * 4096;
    float acc = loadv(bias, q, f32);
#pragma unroll
    for (int ky = 0; ky < 3; ky++)
#pragma unroll
        for (int kx = 0; kx < 3; kx++) {
            int yy = y + 2 * (ky - 1), xx = x + 2 * (kx - 1);
            if (yy >= 0 && yy < 64 && xx >= 0 && xx < 64)
                acc += a[ky * 3 + kx] * v[yy * 64 + xx];
        }
    if (f32) ((float*)out)[g] = acc;
    else     ((__hip_bfloat16*)out)[g] = __float2bfloat16(acc);
}

// ---------------------------------------------------------------------------
// Host orchestration
// ---------------------------------------------------------------------------
extern "C" void kernel_launch(void* const* d_in, const int* in_sizes, int n_in,
                              void* d_out, int out_size, void* d_ws, size_t ws_size,
                              hipStream_t stream)
{
    const void* c1    = d_in[0];
    const void* c2    = d_in[1];
    const void* x     = d_in[2];
    const void* rf1_w = d_in[3];
    const void* rf1_s = d_in[4];
    const void* rf1_b = d_in[5];
    const void* rf2_w = d_in[6];
    const void* rf2_s = d_in[7];
    const void* rf2_b = d_in[8];
    const void* r2_w  = d_in[9];
    const void* r2_s  = d_in[10];
    const void* r2_b  = d_in[11];
    const void* a0_w  = d_in[12];
    const void* a0_s  = d_in[13];
    const void* a0_b  = d_in[14];
    const void* a1_w  = d_in[15];
    const void* a1_s  = d_in[16];
    const void* a1_b  = d_in[17];
    const void* a2_w  = d_in[18];
    const void* a2_s  = d_in[19];
    const void* a2_b  = d_in[20];
    const void* a3_w  = d_in[21];
    const void* a3_s  = d_in[22];
    const void* a3_b  = d_in[23];
    const void* a4_w  = d_in[24];
    const void* a4_s  = d_in[25];
    const void* a4_b  = d_in[26];
    const void* ap_w  = d_in[27];
    const void* ap_s  = d_in[28];
    const void* ap_b  = d_in[29];
    const void* c6_w  = d_in[30];
    const void* c6_b  = d_in[31];

    // ---- workspace layout (float slots); same F_END as round 4 ----
    const long F_BUFR = 0;          //  262144  rf1 out (64,4096)   [accum]
    const long F_C1R  = 262144;     //  262144  rf2 out (64,4096)   [accum]
    const long F_BUFC = 524288;     //   65536  r2 out (64,1024)    [accum]
    const long F_ASPP = 589824;     //  524288  ap out (512,1024)   [accum]
    const long F_ZP   = 1114112;    //     256  zero page (stays zero)
    const long F_TMP  = 1114368;    //  524288  ASPP branch [accum, reused x4]
    const long F_C2R  = 1638656;    //  262144
    const long F_ATT  = 1900800;    //   36864
    const long F_GAPV = 1937664;    //    4096
    const long F_F4C  = 1941760;    //     512
    const long F_F4CO = 1942272;    //     512
    const long F_VS   = 1942784;    //   19456
    const long F_V    = 1962240;    //   77824
    const long F_FLAG = 2040064;    //      64
    const long F_X2   = 2040128;    // 2097152 float-slots (1024x4096 bf16)
    const long F_W2   = 4137280;    // 9437184 float-slots (9x512x4096 bf16)
    const long F_W1   = 13574464;   // 1048576 float-slots (512x4096 bf16)
    const long F_END  = 14623040;

    float* ws    = (float*)d_ws;
    float* bufR  = ws + F_BUFR;
    float* c1r   = ws + F_C1R;
    float* bufC  = ws + F_BUFC;
    float* aspp  = ws + F_ASPP;
    float* tmp   = ws + F_TMP;
    float* c2r   = ws + F_C2R;
    float* att   = ws + F_ATT;
    float* gapv  = ws + F_GAPV;
    float* f4c   = ws + F_F4C;
    float* f4con = ws + F_F4CO;
    float* Vs    = ws + F_VS;
    float* V     = ws + F_V;
    int*   flag  = (int*)(ws + F_FLAG);
    u16*   X2u   = (u16*)(ws + F_X2);
    u16*   W2u   = (u16*)(ws + F_W2);
    u16*   W1u   = (u16*)(ws + F_W1);
    const u16* zp16 = (const u16*)(ws + F_ZP);

    // sub-allocations inside W2u (idle until seg1) for the refine/r2 phase
    u16* X1u   = W2u;                 // 4096x256  = 1048576 u16
    u16* W9Ru  = W2u + 1048576;       // 9x64x256  =  147456
    u16* X1Bu  = W2u + 1196032;       // 4096x64   =  262144
    u16* W9R2u = W2u + 1458176;       // 9x64x64   =   36864
    u16* X1Cu  = W2u + 1495040;       // 1024x512  =  524288
    u16* W1Ru  = W2u + 2019328;       // 64x512    =   32768
    // sub-allocations inside W1u for the ap stage (after the seg conv is done)
    u16* WAPu  = W1u;                 // 512x512   =  262144
    u16* T2u   = W1u + 262144;        // 1024x512  =  524288

    const bool big = ws_size >= (size_t)F_END * 4;

    // ---- dtype probe + zero accumulators (bufR..aspp + zero page) ----
    detect_kernel<<<1, 256, 0, stream>>>((const u16*)c1, flag);
    zero_kernel<<<1024, 256, 0, stream>>>(ws, 1114368);

    if (big) {
        // ---- refine(c1): repack then two 3x3 dil-2 convs on the fast engine
        xpose_bn<<<dim3(64, 4), 256, 0, stream>>>(c1, X1u, nullptr, nullptr,
                                                  flag, 1, 0, 256, 4096);
        xform_w9<<<dim3(1, 64), 256, 0, stream>>>(rf1_w, W9Ru, flag, 64, 256);
        conv_gemm<1><<<256, 256, 0, stream>>>(W9Ru, X1u, zp16, bufR,
                                              256, 64, 9, 2, 6, 4096, 1, 32, 32, 1);
        xpose_bn<<<dim3(64, 1), 256, 0, stream>>>(bufR, X1Bu, rf1_s, rf1_b,
                                                  flag, 0, 1, 64, 4096);
        xform_w9<<<dim3(1, 64), 256, 0, stream>>>(rf2_w, W9R2u, flag, 64, 64);
        conv_gemm<1><<<64, 256, 0, stream>>>(W9R2u, X1Bu, zp16, c1r,
                                             64, 64, 9, 2, 6, 4096, 1, 32, 32, 0);
        ep_bnrelu<<<1024, 256, 0, stream>>>(c1r, rf2_s, rf2_b, flag, 12, 262144);

        // ---- refine2: 1x1 conv on c2 (fast engine), then resize+bn ----
        xpose_bn<<<dim3(16, 8), 256, 0, stream>>>(c2, X1Cu, nullptr, nullptr,
                                                  flag, 1, 0, 512, 1024);
        xform_w1<<<128, 256, 0, stream>>>(r2_w, W1Ru, flag, 512, 0, 1, 9);
        conv_gemm<1><<<32, 256, 0, stream>>>(W1Ru, X1Cu, zp16, bufC,
                                             512, 64, 1, 0, 5, 1024, 1, 8, 128, 0);
        resize_bn<<<1024, 256, 0, stream>>>(bufC, c2r, r2_s, r2_b, flag, 1);

        attn_kernel<<<1024, 256, 0, stream>>>(c1r, c2r, att);

        gap_kernel<<<1024, 256, 0, stream>>>(x, flag, gapv);
        f4_kernel<<<128, 256, 0, stream>>>(a4_w, gapv, a4_s, a4_b, flag, f4c);
        f4con_kernel<<<128, 256, 0, stream>>>(ap_w, f4c, flag, f4con);

        // ---- one-time repack of x ----
        xpose_bn<<<dim3(16, 64), 256, 0, stream>>>(x, X2u, nullptr, nullptr,
                                                   flag, 1, 0, 4096, 1024);

        // ---- seg0: 1x1 ----
        zero_kernel<<<512, 256, 0, stream>>>(tmp, 524288);
        xform_w1<<<8192, 256, 0, stream>>>(a0_w, W1u, flag, 4096, 0, 1, 12);
        conv_gemm<2><<<256, 256, 0, stream>>>(W1u, X2u, zp16, tmp,
                                              4096, 512, 1, 0, 5, 1024, 4, 8, 512, 1);
        xpose_bn<<<dim3(16, 8), 256, 0, stream>>>(tmp, T2u, a0_s, a0_b,
                                                  flag, 0, 1, 512, 1024);
        xform_w1<<<1024, 256, 0, stream>>>(ap_w, WAPu, flag, 2560, 0, 1, 9);
        conv_gemm<2><<<256, 256, 0, stream>>>(WAPu, T2u, zp16, aspp,
                                              512, 512, 1, 0, 5, 1024, 4, 8, 64, 1);
        // ---- seg1: 3x3 d=12 ----
        zero_kernel<<<512, 256, 0, stream>>>(tmp, 524288);
        xform_w9<<<dim3(16, 512), 256, 0, stream>>>(a1_w, W2u, flag, 512, 4096);
        conv_gemm<2><<<512, 256, 0, stream>>>(W2u, X2u, zp16, tmp,
                                              4096, 512, 9, 12, 5, 1024, 4, 8, 256, 1);
        xpose_bn<<<dim3(16, 8), 256, 0, stream>>>(tmp, T2u, a1_s, a1_b,
                                                  flag, 0, 1, 512, 1024);
        xform_w1<<<1024, 256, 0, stream>>>(ap_w, WAPu, flag, 2560, 512, 1, 9);
        conv_gemm<2><<<256, 256, 0, stream>>>(WAPu, T2u, zp16, aspp,
                                              512, 512, 1, 0, 5, 1024, 4, 8, 64, 1);
        // ---- seg2: 3x3 d=24 ----
        zero_kernel<<<512, 256, 0, stream>>>(tmp, 524288);
        xform_w9<<<dim3(16, 512), 256, 0, stream>>>(a2_w, W2u, flag, 512, 4096);
        conv_gemm<2><<<512, 256, 0, stream>>>(W2u, X2u, zp16, tmp,
                                              4096, 512, 9, 24, 5, 1024, 4, 8, 256, 1);
        xpose_bn<<<dim3(16, 8), 256, 0, stream>>>(tmp, T2u, a2_s, a2_b,
                                                  flag, 0, 1, 512, 1024);
        xform_w1<<<1024, 256, 0, stream>>>(ap_w, WAPu, flag, 2560, 1024, 1, 9);
        conv_gemm<2><<<256, 256, 0, stream>>>(WAPu, T2u, zp16, aspp,
                                              512, 512, 1, 0, 5, 1024, 4, 8, 64, 1);
        // ---- seg3: 3x3 d=36 -> center tap only ----
        zero_kernel<<<512, 256, 0, stream>>>(tmp, 524288);
        xform_w1<<<8192, 256, 0, stream>>>(a3_w, W1u, flag, 36864, 4, 9, 12);
        conv_gemm<2><<<256, 256, 0, stream>>>(W1u, X2u, zp16, tmp,
                                              4096, 512, 1, 0, 5, 1024, 4, 8, 512, 1);
        xpose_bn<<<dim3(16, 8), 256, 0, stream>>>(tmp, T2u, a3_s, a3_b,
                                                  flag, 0, 1, 512, 1024);
        xform_w1<<<1024, 256, 0, stream>>>(ap_w, WAPu, flag, 2560, 1536, 1, 9);
        conv_gemm<2><<<256, 256, 0, stream>>>(WAPu, T2u, zp16, aspp,
                                              512, 512, 1, 0, 5, 1024, 4, 8, 64, 1);
        // ---- ASPP epilogue ----
        ep_aspp<<<2048, 256, 0, stream>>>(aspp, f4con, ap_s, ap_b, flag);
    } else {
        // ---- fallback: old engine end-to-end ----
        conv_mfma<<<dim3(1, 32, 4), 256, 0, stream>>>(rf1_w, c1, bufR, flag, 1,
                                                      256, 256 * 9, 9, 0, 9, 2, 6);
        ep_bnrelu<<<1024, 256, 0, stream>>>(bufR, rf1_s, rf1_b, flag, 12, 262144);
        conv_mfma<<<dim3(1, 32, 2), 256, 0, stream>>>(rf2_w, bufR, c1r, flag, 0,
                                                      64, 64 * 9, 9, 0, 9, 2, 6);
        ep_bnrelu<<<1024, 256, 0, stream>>>(c1r, rf2_s, rf2_b, flag, 12, 262144);
        conv_mfma<<<dim3(1, 8, 4), 256, 0, stream>>>(r2_w, c2, bufC, flag, 1,
                                                     512, 512, 1, 0, 1, 0, 5);
        resize_bn<<<1024, 256, 0, stream>>>(bufC, c2r, r2_s, r2_b, flag, 1);
        attn_kernel<<<1024, 256, 0, stream>>>(c1r, c2r, att);
        gap_kernel<<<1024, 256, 0, stream>>>(x, flag, gapv);
        f4_kernel<<<128, 256, 0, stream>>>(a4_w, gapv, a4_s, a4_b, flag, f4c);
        f4con_kernel<<<128, 256, 0, stream>>>(ap_w, f4c, flag, f4con);

        zero_kernel<<<512, 256, 0, stream>>>(tmp, 524288);
        conv_mfma<<<dim3(8, 8, 4), 256, 0, stream>>>(a0_w, x, tmp, flag, 1,
                                                     4096, 4096, 1, 0, 1, 0, 5);
        ep_bnrelu<<<2048, 256, 0, stream>>>(tmp, a0_s, a0_b, flag, 10, 524288);
        conv_mfma<<<dim3(8, 8, 2), 256, 0, stream>>>(ap_w, tmp, aspp, flag, 0,
                                                     512, 2560, 1, 0, 1, 0, 5);
        zero_kernel<<<512, 256, 0, stream>>>(tmp, 524288);
        conv_mfma<<<dim3(8, 8, 8), 256, 0, stream>>>(a1_w, x, tmp, flag, 1,
                                                     4096, 4096 * 9, 9, 0, 9, 12, 5);
        ep_bnrelu<<<2048, 256, 0, stream>>>(tmp, a1_s, a1_b, flag, 10, 524288);
        conv_mfma<<<dim3(8, 8, 2), 256, 0, stream>>>(ap_w, tmp, aspp, flag, 0,
                                                     512, 2560, 1, 512, 1, 0, 5);
        zero_kernel<<<512, 256, 0, stream>>>(tmp, 524288);
        conv_mfma<<<dim3(8, 8, 8), 256, 0, stream>>>(a2_w, x, tmp, flag, 1,
                                                     4096, 4096 * 9, 9, 0, 9, 24, 5);
        ep_bnrelu<<<2048, 256, 0, stream>>>(tmp, a2_s, a2_b, flag, 10, 524288);
        conv_mfma<<<dim3(8, 8, 2), 256, 0, stream>>>(ap_w, tmp, aspp, flag, 0,
                                                     512, 2560, 1, 1024, 1, 0, 5);
        zero_kernel<<<512, 256, 0, stream>>>(tmp, 524288);
        conv_mfma<<<dim3(8, 8, 4), 256, 0, stream>>>(a3_w, x, tmp, flag, 1,
                                                     4096, 4096 * 9, 9, 4, 1, 0, 5);
        ep_bnrelu<<<2048, 256, 0, stream>>>(tmp, a3_s, a3_b, flag, 10, 524288);
        conv_mfma<<<dim3(8, 8, 2), 256, 0, stream>>>(ap_w, tmp, aspp, flag, 0,
                                                     512, 2560, 1, 1536, 1, 0, 5);
        ep_aspp<<<2048, 256, 0, stream>>>(aspp, f4con, ap_s, ap_b, flag);
    }

    // ---- tail: c6 on 32x32, resize to 64x64, attention aggregation ----
    vs_kernel<<<dim3(4, 19), 256, 0, stream>>>(aspp, c6_w, flag, Vs);
    resize_bn<<<304, 256, 0, stream>>>(Vs, V, nullptr, nullptr, flag, 0);
    final_kernel<<<304, 256, 0, stream>>>(att, V, c6_b, flag, d_out);
}

// Round 3
// 673.401 us; speedup vs baseline: 2.5045x; 1.0862x over previous
//
#include <hip/hip_runtime.h>
#include <hip/hip_bf16.h>

// ---------------------------------------------------------------------------
// up_deeplabv3Head — round 6: counted-vmcnt deep pipeline in conv_gemm
// (4 LDS buffers, depth-3 prefetch, raw s_barrier, never vmcnt(0) mid-loop),
// plus fusion of the four ap 1x1 convs into one K=2048 GEMM.
// ---------------------------------------------------------------------------

typedef unsigned short u16;
typedef short bf16x8 __attribute__((ext_vector_type(8)));
typedef float f32x4  __attribute__((ext_vector_type(4)));
typedef u16   u16x8  __attribute__((ext_vector_type(8)));

__device__ __forceinline__ float bf2f(u16 u) {
    return __uint_as_float(((unsigned int)u) << 16);
}
__device__ __forceinline__ u16 f2bf(float f) {   // round-to-nearest-even
    unsigned u = __float_as_uint(f);
    return (u16)((u + 0x7FFFu + ((u >> 16) & 1u)) >> 16);
}
// flag f32: 1 -> storage fp32, 0 -> storage bf16
__device__ __forceinline__ float loadv(const void* p, long i, int f32) {
    return f32 ? ((const float*)p)[i] : bf2f(((const u16*)p)[i]);
}
__device__ __forceinline__ u16 loadbf(const void* p, long i, int f32) {
    return f32 ? f2bf(((const float*)p)[i]) : ((const u16*)p)[i];
}

__device__ __forceinline__ void gload16(const u16* g, u16* l) {
    __builtin_amdgcn_global_load_lds(
        (const __attribute__((address_space(1))) unsigned int*)(g),
        (__attribute__((address_space(3))) unsigned int*)(l), 16, 0, 0);
}

// ---------------------------------------------------------------------------
// dtype probe (verified): bf16-stored N(0,1) has ~0 large-exponent words.
// ---------------------------------------------------------------------------
__global__ __launch_bounds__(256) void detect_kernel(
    const u16* __restrict__ c1, int* __restrict__ flag)
{
    __shared__ int cnt;
    if (threadIdx.x == 0) cnt = 0;
    __syncthreads();
    int local = 0;
    for (int i = threadIdx.x; i < 16384; i += 256) {
        u16 u = c1[i];
        if ((u & 0x7F80) >= 0x4F00) local++;
    }
    atomicAdd(&cnt, local);
    __syncthreads();
    if (threadIdx.x == 0) flag[0] = (cnt > 256) ? 1 : 0;
}

__global__ __launch_bounds__(256) void zero_kernel(float* __restrict__ p, int n)
{
    for (int g = blockIdx.x * 256 + threadIdx.x; g < n; g += gridDim.x * 256)
        p[g] = 0.f;
}

// ---------------------------------------------------------------------------
// Generic repack kernels
// ---------------------------------------------------------------------------

// src [C][P] (f32 if !flagged, else flag-dtype) -> dst [P][dstC] bf16 at col
// offset coff. Optional fused bn+relu per channel. Grid (P/64, C/64).
__global__ __launch_bounds__(256) void xpose_bn(
    const void* __restrict__ src, u16* __restrict__ dst,
    const void* __restrict__ s, const void* __restrict__ b,
    const int* __restrict__ flag, int flagged, int dobn, int C, int P,
    int dstC, int coff)
{
    __shared__ u16 T[64][72];
    const int fl = flag[0];
    const int srcf32 = flagged ? fl : 1;
    const int p0 = blockIdx.x * 64, c0 = blockIdx.y * 64;
    const int t = threadIdx.x;
    {
        int c = t >> 2, pq = (t & 3) * 16;
        float sc = 1.f, bc = 0.f;
        if (dobn) { sc = loadv(s, c0 + c, fl); bc = loadv(b, c0 + c, fl); }
        const long sb = (long)(c0 + c) * P + p0 + pq;
        if (srcf32) {
            const float* sp = (const float*)src + sb;
#pragma unroll
            for (int i = 0; i < 16; i += 4) {
                float4 v = *(const float4*)(sp + i);
                float vv[4] = {v.x, v.y, v.z, v.w};
#pragma unroll
                for (int j = 0; j < 4; j++) {
                    float u = vv[j];
                    if (dobn) u = fmaxf(u * sc + bc, 0.f);
                    T[pq + i + j][c] = f2bf(u);
                }
            }
        } else {
            const u16* sp = (const u16*)src + sb;
#pragma unroll
            for (int i = 0; i < 16; i++) T[pq + i][c] = sp[i];
        }
    }
    __syncthreads();
    {
        int p = t >> 2, cq = (t & 3) * 16;
        u16x8 v0, v1;
#pragma unroll
        for (int i = 0; i < 8; i++) { v0[i] = T[p][cq + i]; v1[i] = T[p][cq + 8 + i]; }
        *(u16x8*)&dst[(long)(p0 + p) * dstC + coff + c0 + cq] = v0;
        *(u16x8*)&dst[(long)(p0 + p) * dstC + coff + c0 + cq + 8] = v1;
    }
}

// w [O][C][9] -> W9 [9][O][C] bf16. Grid (ceil(C/256), O).
__global__ __launch_bounds__(256) void xform_w9(
    const void* __restrict__ w, u16* __restrict__ W9, const int* __restrict__ flag,
    int O, int C)
{
    const int f32 = flag[0];
    const int o = blockIdx.y;
    const int c = blockIdx.x * 256 + threadIdx.x;
    if (c >= C) return;
    const long src = ((long)o * C + c) * 9;
    u16 v[9];
    if (f32) {
        const float* p = (const float*)w + src;
#pragma unroll
        for (int j = 0; j < 9; j++) v[j] = f2bf(p[j]);
    } else {
        const u16* p = (const u16*)w + src;
#pragma unroll
        for (int j = 0; j < 9; j++) v[j] = p[j];
    }
#pragma unroll
    for (int j = 0; j < 9; j++)
        W9[(long)j * O * C + (long)o * C + c] = v[j];
}

// generic 1-plane extract: Wo[o*C + c] = w[o*ldi + off + c*st] as bf16.
// Grid O*C/256, C = 1<<logC.
__global__ __launch_bounds__(256) void xform_w1(
    const void* __restrict__ w, u16* __restrict__ Wo, const int* __restrict__ flag,
    int ldi, int off, int st, int logC)
{
    const int f32 = flag[0];
    long g = (long)blockIdx.x * 256 + threadIdx.x;
    long o = g >> logC;
    int c = (int)(g & ((1 << logC) - 1));
    Wo[g] = loadbf(w, o * ldi + off + (long)c * st, f32);
}

// ---------------------------------------------------------------------------
// conv_gemm<MF>: OUT[o,p] += sum_{t in mask, c} W2[t][o][c] * X2[p+shift(t)][c]
// Tile: (MF*64) o x 128 px, 4 waves, MF m-frags x 8 n-frags per wave.
// 4-buffer LDS, depth-3 prefetch with COUNTED vmcnt (never 0 mid-loop),
// raw s_barrier + sched_barrier(0). XOR swizzle byte ^= ((byte>>7)&3)<<4.
// 1-D grid, XCD-aware decode (grid%8==0 when swz=1). Split-K + atomicAdd.
// ---------------------------------------------------------------------------
template<int MF>
__global__ __launch_bounds__(256, 4) void conv_gemm(
    const u16* __restrict__ W2, const u16* __restrict__ X2,
    const u16* __restrict__ zpage, float* __restrict__ OUT,
    int K, int O, int taps, int d, int logIW, int P,
    int nbo, int nbp, int kcs, int swz)
{
    __shared__ __align__(16) u16 Ws[4][MF * 2048];
    __shared__ __align__(16) u16 Xs[4][4096];

    const int tid = threadIdx.x;
    int bo, bp, bz;
    {
        int pid = blockIdx.x;
        if (swz) {
            int xcd = pid & 7, j = pid >> 3;
            bp = j % nbp;
            int g = j / nbp;
            int G = xcd + 8 * g;
            bo = G % nbo; bz = G / nbo;
        } else {
            bp = pid % nbp;
            int q = pid / nbp;
            bo = q % nbo; bz = q / nbo;
        }
    }
    const int kb = bz * kcs;
    const int IW = 1 << logIW;

    const int wave = tid >> 6, lane = tid & 63;
    const int quad = lane >> 4, l15 = lane & 15;

    // uniform valid-tap mask over this tile's row band
    int mask = 1;
    if (taps == 9) {
        const int rb = 128 >> logIW;
        const int ty0 = bp * rb;
        mask = 0;
        for (int t = 0; t < 9; t++) {
            int dy = (t / 3 - 1) * d;
            if (ty0 + rb - 1 + dy >= 0 && ty0 + dy < IW) mask |= (1 << t);
        }
    }
    const int nIt = (kcs >> 5) * __popc(mask);

    // per-thread staging decode: physical dest byte b holds logical l
    int wrow[MF], wk[MF];
#pragma unroll
    for (int li = 0; li < MF; li++) {
        int bb = li * 4096 + tid * 16;
        int l = bb ^ (((bb >> 7) & 3) << 4);
        wrow[li] = l >> 6; wk[li] = ((l >> 4) & 3) * 8;
    }
    int xrow[2], xk[2];
#pragma unroll
    for (int li = 0; li < 2; li++) {
        int bb = li * 4096 + tid * 16;
        int l = bb ^ (((bb >> 7) & 3) << 4);
        xrow[li] = l >> 6; xk[li] = ((l >> 4) & 3) * 8;
    }

    const long wplane = (long)O * K;

    f32x4 acc[MF][8];
#pragma unroll
    for (int mi = 0; mi < MF; mi++)
#pragma unroll
        for (int j = 0; j < 8; j++) {
            f32x4 z = {0.f, 0.f, 0.f, 0.f};
            acc[mi][j] = z;
        }

    int arow[MF];
#pragma unroll
    for (int mi = 0; mi < MF; mi++) {
        int ao = (wave * (MF * 16) + mi * 16 + l15) * 64 + quad * 16;
        arow[mi] = ao ^ (((ao >> 7) & 3) << 4);
    }

    int tt = __ffs(mask) - 1;
    int kc = kb;

    auto STAGE = [&](int buf) {
        int dy = 0, dx = 0;
        if (taps == 9) { dy = (tt / 3 - 1) * d; dx = (tt % 3 - 1) * d; }
#pragma unroll
        for (int li = 0; li < MF; li++)
            gload16(W2 + (long)tt * wplane + (long)(bo * (MF * 64) + wrow[li]) * K + kc + wk[li],
                    &Ws[buf][li * 2048 + tid * 8]);
#pragma unroll
        for (int li = 0; li < 2; li++) {
            int pg = bp * 128 + xrow[li];
            const u16* src;
            if (taps == 9) {
                int yy = (pg >> logIW) + dy, xx = (pg & (IW - 1)) + dx;
                src = ((unsigned)yy < (unsigned)IW && (unsigned)xx < (unsigned)IW)
                    ? X2 + (long)((yy << logIW) | xx) * K + kc + xk[li] : zpage;
            } else {
                src = X2 + (long)pg * K + kc + xk[li];
            }
            gload16(src, &Xs[buf][li * 2048 + tid * 8]);
        }
        int rem = mask >> (tt + 1);
        if (rem) tt += __ffs(rem);
        else { tt = __ffs(mask) - 1; kc += 32; }
    };

    // prologue: stage up to 3 tiles ahead
    STAGE(0);
    if (nIt > 1) STAGE(1);
    if (nIt > 2) STAGE(2);

    for (int i = 0; i < nIt; i++) {
        // counted wait: leave the (up to 3) not-yet-needed stages in flight.
        // loads/stage/thread L = MF + 2.
        const int ex = nIt - 1 - i;
        if constexpr (MF == 2) {
            if (ex >= 3)      asm volatile("s_waitcnt vmcnt(12)" ::: "memory");
            else if (ex == 2) asm volatile("s_waitcnt vmcnt(8)" ::: "memory");
            else if (ex == 1) asm volatile("s_waitcnt vmcnt(4)" ::: "memory");
            else              asm volatile("s_waitcnt vmcnt(0)" ::: "memory");
        } else {
            if (ex >= 3)      asm volatile("s_waitcnt vmcnt(9)" ::: "memory");
            else if (ex == 2) asm volatile("s_waitcnt vmcnt(6)" ::: "memory");
            else if (ex == 1) asm volatile("s_waitcnt vmcnt(3)" ::: "memory");
            else              asm volatile("s_waitcnt vmcnt(0)" ::: "memory");
        }
        __builtin_amdgcn_s_barrier();
        __builtin_amdgcn_sched_barrier(0);   // nothing (ds_read/gload) crosses

        const int cur = i & 3;
        bf16x8 a[MF];
#pragma unroll
        for (int mi = 0; mi < MF; mi++)
            a[mi] = *(const bf16x8*)&Ws[cur][arow[mi] >> 1];
#pragma unroll
        for (int j = 0; j < 8; j++) {
            int boff = (j * 16 + l15) * 64 + quad * 16;
            boff ^= ((boff >> 7) & 3) << 4;
            bf16x8 b = *(const bf16x8*)&Xs[cur][boff >> 1];
#pragma unroll
            for (int mi = 0; mi < MF; mi++)
                acc[mi][j] = __builtin_amdgcn_mfma_f32_16x16x32_bf16(a[mi], b, acc[mi][j], 0, 0, 0);
        }
        if (i + 3 < nIt) STAGE((i + 3) & 3);
    }

#pragma unroll
    for (int mi = 0; mi < MF; mi++)
#pragma unroll
        for (int j = 0; j < 8; j++) {
            int pgl = bp * 128 + j * 16 + l15;
            long ob = (long)(bo * (MF * 64) + wave * (MF * 16) + mi * 16 + quad * 4);
#pragma unroll
            for (int r = 0; r < 4; r++)
                atomicAdd(&OUT[(ob + r) * P + pgl], acc[mi][j][r]);
        }
}

// ---------------------------------------------------------------------------
// Old general MFMA conv (small-workspace fallback path only)
// ---------------------------------------------------------------------------
__global__ __launch_bounds__(256) void conv_mfma(
    const void* __restrict__ W, const void* __restrict__ X, float* __restrict__ OUT,
    const int* __restrict__ flag, int x_ext,
    int K, int wrow, int wstride, int woff, int taps, int d, int logIW)
{
    __shared__ __align__(16) u16 Ws[64 * 40];
    __shared__ __align__(16) u16 Xs[128 * 40];

    const int IW = 1 << logIW;
    const int NP = IW * IW;
    const int wf32 = flag[0];
    const int xf32 = x_ext ? wf32 : 1;

    const int tid = threadIdx.x;
    const int bo = blockIdx.x, bp = blockIdx.y;
    const int kcs = K / gridDim.z;
    const int kb = blockIdx.z * kcs;

    const int w_o = tid >> 2, w_kg = (tid & 3) * 8;
    const int x_p = tid >> 1, x_kg = (tid & 1) * 16;
    const int pg  = bp * 128 + x_p;
    const int py  = pg >> logIW, px = pg & (IW - 1);
    const int ty0 = (bp * 128) >> logIW;
    const int ty1 = ty0 + (128 >> logIW) - 1;

    const int wave = tid >> 6, lane = tid & 63;
    const int quad = lane >> 4, l15 = lane & 15;

    f32x4 acc[8];
#pragma unroll
    for (int j = 0; j < 8; j++) {
        f32x4 z = {0.f, 0.f, 0.f, 0.f};
        acc[j] = z;
    }

    const long wbase_o = (long)(bo * 64 + w_o) * wrow + woff;

    for (int kc = kb; kc < kb + kcs; kc += 32) {
        for (int t = 0; t < taps; t++) {
            int dy = 0, dx = 0, wt = 0;
            if (taps == 9) { dy = (t / 3 - 1) * d; dx = (t % 3 - 1) * d; wt = t; }
            if (ty1 + dy < 0 || ty0 + dy >= IW) continue;

            {
                u16 tv[8];
                if (wstride == 1) {
                    long idx = wbase_o + kc + w_kg;
                    if (wf32) {
                        float4 v0 = *(const float4*)((const float*)W + idx);
                        float4 v1 = *(const float4*)((const float*)W + idx + 4);
                        tv[0] = f2bf(v0.x); tv[1] = f2bf(v0.y);
                        tv[2] = f2bf(v0.z); tv[3] = f2bf(v0.w);
                        tv[4] = f2bf(v1.x); tv[5] = f2bf(v1.y);
                        tv[6] = f2bf(v1.z); tv[7] = f2bf(v1.w);
                    } else {
                        ushort4 v0 = *(const ushort4*)((const u16*)W + idx);
                        ushort4 v1 = *(const ushort4*)((const u16*)W + idx + 4);
                        tv[0] = v0.x; tv[1] = v0.y; tv[2] = v0.z; tv[3] = v0.w;
                        tv[4] = v1.x; tv[5] = v1.y; tv[6] = v1.z; tv[7] = v1.w;
                    }
                } else {
                    long idx = wbase_o + wt + (long)(kc + w_kg) * 9;
#pragma unroll
                    for (int i = 0; i < 8; i++)
                        tv[i] = loadbf(W, idx + (long)i * 9, wf32);
                }
                *(ushort4*)&Ws[w_o * 40 + w_kg]     = make_ushort4(tv[0], tv[1], tv[2], tv[3]);
                *(ushort4*)&Ws[w_o * 40 + w_kg + 4] = make_ushort4(tv[4], tv[5], tv[6], tv[7]);
            }
            {
                int yy = py + dy, xv = px + dx;
                bool ok = ((unsigned)yy < (unsigned)IW) && ((unsigned)xv < (unsigned)IW);
                u16 tv[16];
                if (ok) {
                    long idx = (long)(kc + x_kg) * NP + yy * IW + xv;
                    if (xf32) {
#pragma unroll
                        for (int i = 0; i < 16; i++)
                            tv[i] = f2bf(((const float*)X)[idx + (long)i * NP]);
                    } else {
#pragma unroll
                        for (int i = 0; i < 16; i++)
                            tv[i] = ((const u16*)X)[idx + (long)i * NP];
                    }
                } else {
#pragma unroll
                    for (int i = 0; i < 16; i++) tv[i] = 0;
                }
                *(ushort4*)&Xs[x_p * 40 + x_kg]      = make_ushort4(tv[0], tv[1], tv[2], tv[3]);
                *(ushort4*)&Xs[x_p * 40 + x_kg + 4]  = make_ushort4(tv[4], tv[5], tv[6], tv[7]);
                *(ushort4*)&Xs[x_p * 40 + x_kg + 8]  = make_ushort4(tv[8], tv[9], tv[10], tv[11]);
                *(ushort4*)&Xs[x_p * 40 + x_kg + 12] = make_ushort4(tv[12], tv[13], tv[14], tv[15]);
            }
            __syncthreads();
            {
                bf16x8 a = *(const bf16x8*)&Ws[(wave * 16 + l15) * 40 + quad * 8];
#pragma unroll
                for (int j = 0; j < 8; j++) {
                    bf16x8 b = *(const bf16x8*)&Xs[(j * 16 + l15) * 40 + quad * 8];
                    acc[j] = __builtin_amdgcn_mfma_f32_16x16x32_bf16(a, b, acc[j], 0, 0, 0);
                }
            }
            __syncthreads();
        }
    }

#pragma unroll
    for (int j = 0; j < 8; j++) {
        int pgl = bp * 128 + j * 16 + l15;
        long ob = (long)(bo * 64 + wave * 16 + quad * 4);
#pragma unroll
        for (int r = 0; r < 4; r++)
            atomicAdd(&OUT[(ob + r) * NP + pgl], acc[j][r]);
    }
}

// bn+relu in place over (C, N) f32, N = 2^logN
__global__ __launch_bounds__(256) void ep_bnrelu(
    float* __restrict__ buf, const void* __restrict__ s, const void* __restrict__ b,
    const int* __restrict__ flag, int logN, int total)
{
    int f32 = flag[0];
    int g = blockIdx.x * 256 + threadIdx.x;
    if (g >= total) return;
    int c = g >> logN;
    float v = buf[g] * loadv(s, c, f32) + loadv(b, c, f32);
    buf[g] = fmaxf(v, 0.f);
}

__global__ __launch_bounds__(256) void ep_aspp(
    float* __restrict__ buf, const float* __restrict__ f4con,
    const void* __restrict__ s, const void* __restrict__ b, const int* __restrict__ flag)
{
    int f32 = flag[0];
    int g = blockIdx.x * 256 + threadIdx.x;
    int c = g >> 10;
    float v = (buf[g] + f4con[c]) * loadv(s, c, f32) + loadv(b, c, f32);
    buf[g] = fmaxf(v, 0.f);
}

__global__ __launch_bounds__(256) void resize_bn(
    const float* __restrict__ in, float* __restrict__ out,
    const void* __restrict__ s, const void* __restrict__ b,
    const int* __restrict__ flag, int dobn)
{
    int g = blockIdx.x * 256 + threadIdx.x;
    int c = g >> 12, p = g & 4095;
    int oy = p >> 6, ox = p & 63;
    const float r = 31.0f / 63.0f;
    float tyf = oy * r, txf = ox * r;
    int y0 = (int)tyf, x0 = (int)txf;
    float fy = tyf - y0, fx = txf - x0;
    int y1 = y0 + 1 > 31 ? 31 : y0 + 1;
    int x1 = x0 + 1 > 31 ? 31 : x0 + 1;
    const float* pc = in + c * 1024;
    float v00 = pc[y0 * 32 + x0], v01 = pc[y0 * 32 + x1];
    float v10 = pc[y1 * 32 + x0], v11 = pc[y1 * 32 + x1];
    float v = (1.f - fy) * ((1.f - fx) * v00 + fx * v01) +
              fy * ((1.f - fx) * v10 + fx * v11);
    if (dobn) v = fmaxf(v * loadv(s, c, flag[0]) + loadv(b, c, flag[0]), 0.f);
    out[g] = v;
}

__global__ __launch_bounds__(256) void attn_kernel(
    const float* __restrict__ c1r, const float* __restrict__ c2r, float* __restrict__ att)
{
    int tid = threadIdx.x;
    int p = blockIdx.x * 4 + (tid >> 6);
    int lane = tid & 63;
    int y = p >> 6, x = p & 63;
    float a = c1r[lane * 4096 + p];
    float e[9];
#pragma unroll
    for (int ky = 0; ky < 3; ky++)
#pragma unroll
        for (int kx = 0; kx < 3; kx++) {
            int yy = y + 2 * (ky - 1), xx = x + 2 * (kx - 1);
            float v = 0.f;
            if (yy >= 0 && yy < 64 && xx >= 0 && xx < 64)
                v = a * c2r[lane * 4096 + yy * 64 + xx];
#pragma unroll
            for (int off = 32; off; off >>= 1) v += __shfl_xor(v, off);
            e[ky * 3 + kx] = v;
        }
    float m = e[0];
#pragma unroll
    for (int k = 1; k < 9; k++) m = fmaxf(m, e[k]);
    float ssum = 0.f;
#pragma unroll
    for (int k = 0; k < 9; k++) ssum += __expf(e[k] - m);
    if (lane < 9) {
        float mye = e[0];
#pragma unroll
        for (int k = 1; k < 9; k++)
            if (lane == k) mye = e[k];
        att[p * 9 + lane] = __expf(mye - m) / ssum;
    }
}

__global__ __launch_bounds__(256) void gap_kernel(
    const void* __restrict__ x, const int* __restrict__ flag, float* __restrict__ gap)
{
    int f32 = flag[0];
    int tid = threadIdx.x;
    int c = blockIdx.x * 4 + (tid >> 6);
    int lane = tid & 63;
    long base = (long)c * 1024;
    float ssum = 0.f;
#pragma unroll
    for (int i = 0; i < 16; i++) ssum += loadv(x, base + lane + i * 64, f32);
#pragma unroll
    for (int off = 32; off; off >>= 1) ssum += __shfl_xor(ssum, off);
    if (lane == 0) gap[c] = ssum * (1.0f / 1024.0f);
}

__global__ __launch_bounds__(256) void f4_kernel(
    const void* __restrict__ w, const float* __restrict__ gap,
    const void* __restrict__ s, const void* __restrict__ b,
    const int* __restrict__ flag, float* __restrict__ f4c)
{
    int f32 = flag[0];
    int tid = threadIdx.x;
    int o = blockIdx.x * 4 + (tid >> 6);
    int lane = tid & 63;
    long base = (long)o * 4096;
    float ssum = 0.f;
#pragma unroll
    for (int i = 0; i < 64; i++)
        ssum += loadv(w, base + lane + i * 64, f32) * gap[lane + i * 64];
#pragma unroll
    for (int off = 32; off; off >>= 1) ssum += __shfl_xor(ssum, off);
    if (lane == 0) f4c[o] = fmaxf(ssum * loadv(s, o, f32) + loadv(b, o, f32), 0.f);
}

__global__ __launch_bounds__(256) void f4con_kernel(
    const void* __restrict__ ap_w, const float* __restrict__ f4c,
    const int* __restrict__ flag, float* __restrict__ f4con)
{
    int f32 = flag[0];
    int tid = threadIdx.x;
    int o = blockIdx.x * 4 + (tid >> 6);
    int lane = tid & 63;
    long base = (long)o * 2560 + 2048;
    float ssum = 0.f;
#pragma unroll
    for (int i = 0; i < 8; i++)
        ssum += loadv(ap_w, base + lane + i * 64, f32) * f4c[lane + i * 64];
#pragma unroll
    for (int off = 32; off; off >>= 1) ssum += __shfl_xor(ssum, off);
    if (lane == 0) f4con[o] = ssum;
}

__global__ __launch_bounds__(256) void vs_kernel(
    const float* __restrict__ aspp, const void* __restrict__ w,
    const int* __restrict__ flag, float* __restrict__ Vs)
{
    int f32 = flag[0];
    int p = blockIdx.x * 256 + threadIdx.x;
    int q = blockIdx.y;
    long wb = (long)q * 512;
    float a0 = 0.f, a1 = 0.f, a2 = 0.f, a3 = 0.f;
    for (int c = 0; c < 512; c += 4) {
        a0 = fmaf(loadv(w, wb + c + 0, f32), aspp[(c + 0) * 1024 + p], a0);
        a1 = fmaf(loadv(w, wb + c + 1, f32), aspp[(c + 1) * 1024 + p], a1);
        a2 = fmaf(loadv(w, wb + c + 2, f32), aspp[(c + 2) * 1024 + p], a2);
        a3 = fmaf(loadv(w, wb + c + 3, f32), aspp[(c + 3) * 1024 + p], a3);
    }
    Vs[q * 1024 + p] = (a0 + a1) + (a2 + a3);
}

__global__ __launch_bounds__(256) void final_kernel(
    const float* __restrict__ att, const float* __restrict__ V,
    const void* __restrict__ bias, const int* __restrict__ flag, void* __restrict__ out)
{
    int f32 = flag[0];
    int g = blockIdx.x * 256 + threadIdx.x;
    int q = g >> 12, p = g & 4095;
    int y = p >> 6, x = p & 63;
    const float* a = att + p * 9;
    const float* v = V + q * 4096;
    float acc = loadv(bias, q, f32);
#pragma unroll
    for (int ky = 0; ky < 3; ky++)
#pragma unroll
        for (int kx = 0; kx < 3; kx++) {
            int yy = y + 2 * (ky - 1), xx = x + 2 * (kx - 1);
            if (yy >= 0 && yy < 64 && xx >= 0 && xx < 64)
                acc += a[ky * 3 + kx] * v[yy * 64 + xx];
        }
    if (f32) ((float*)out)[g] = acc;
    else     ((__hip_bfloat16*)out)[g] = __float2bfloat16(acc);
}

// ---------------------------------------------------------------------------
// Host orchestration
// ---------------------------------------------------------------------------
extern "C" void kernel_launch(void* const* d_in, const int* in_sizes, int n_in,
                              void* d_out, int out_size, void* d_ws, size_t ws_size,
                              hipStream_t stream)
{
    const void* c1    = d_in[0];
    const void* c2    = d_in[1];
    const void* x     = d_in[2];
    const void* rf1_w = d_in[3];
    const void* rf1_s = d_in[4];
    const void* rf1_b = d_in[5];
    const void* rf2_w = d_in[6];
    const void* rf2_s = d_in[7];
    const void* rf2_b = d_in[8];
    const void* r2_w  = d_in[9];
    const void* r2_s  = d_in[10];
    const void* r2_b  = d_in[11];
    const void* a0_w  = d_in[12];
    const void* a0_s  = d_in[13];
    const void* a0_b  = d_in[14];
    const void* a1_w  = d_in[15];
    const void* a1_s  = d_in[16];
    const void* a1_b  = d_in[17];
    const void* a2_w  = d_in[18];
    const void* a2_s  = d_in[19];
    const void* a2_b  = d_in[20];
    const void* a3_w  = d_in[21];
    const void* a3_s  = d_in[22];
    const void* a3_b  = d_in[23];
    const void* a4_w  = d_in[24];
    const void* a4_s  = d_in[25];
    const void* a4_b  = d_in[26];
    const void* ap_w  = d_in[27];
    const void* ap_s  = d_in[28];
    const void* ap_b  = d_in[29];
    const void* c6_w  = d_in[30];
    const void* c6_b  = d_in[31];

    // ---- workspace layout (float slots); same F_END as round 4/5 ----
    const long F_BUFR = 0;          //  262144  rf1 out (64,4096)   [accum]
    const long F_C1R  = 262144;     //  262144  rf2 out (64,4096)   [accum]
    const long F_BUFC = 524288;     //   65536  r2 out (64,1024)    [accum]
    const long F_ASPP = 589824;     //  524288  ap out (512,1024)   [accum]
    const long F_ZP   = 1114112;    //     256  zero page (stays zero)
    const long F_TMP  = 1114368;    //  524288  ASPP branch [accum, reused x4]
    const long F_C2R  = 1638656;    //  262144
    const long F_ATT  = 1900800;    //   36864
    const long F_GAPV = 1937664;    //    4096
    const long F_F4C  = 1941760;    //     512
    const long F_F4CO = 1942272;    //     512
    const long F_VS   = 1942784;    //   19456
    const long F_V    = 1962240;    //   77824
    const long F_FLAG = 2040064;    //      64
    const long F_X2   = 2040128;    // 2097152 float-slots (1024x4096 bf16)
    const long F_W2   = 4137280;    // 9437184 float-slots (9x512x4096 bf16)
    const long F_W1   = 13574464;   // 1048576 float-slots -> T2all (1024x2048 bf16)
    const long F_END  = 14623040;

    float* ws    = (float*)d_ws;
    float* bufR  = ws + F_BUFR;
    float* c1r   = ws + F_C1R;
    float* bufC  = ws + F_BUFC;
    float* aspp  = ws + F_ASPP;
    float* tmp   = ws + F_TMP;
    float* c2r   = ws + F_C2R;
    float* att   = ws + F_ATT;
    float* gapv  = ws + F_GAPV;
    float* f4c   = ws + F_F4C;
    float* f4con = ws + F_F4CO;
    float* Vs    = ws + F_VS;
    float* V     = ws + F_V;
    int*   flag  = (int*)(ws + F_FLAG);
    u16*   X2u   = (u16*)(ws + F_X2);
    u16*   W2u   = (u16*)(ws + F_W2);
    u16*   T2all = (u16*)(ws + F_W1);   // [1024][2048] bf16 (four 512-ch segs)
    const u16* zp16 = (const u16*)(ws + F_ZP);

    // sub-allocations inside W2u (idle until seg1) for the refine/r2 phase
    u16* X1u   = W2u;                 // 4096x256  = 1048576 u16
    u16* W9Ru  = W2u + 1048576;       // 9x64x256  =  147456
    u16* X1Bu  = W2u + 1196032;       // 4096x64   =  262144
    u16* W9R2u = W2u + 1458176;       // 9x64x64   =   36864
    u16* X1Cu  = W2u + 1495040;       // 1024x512  =  524288
    u16* W1Ru  = W2u + 2019328;       // 64x512    =   32768
    // W2u re-use within ASPP stream (all sequential, stream-ordered):
    u16* a0Wu  = W2u;                 // 512x4096  = 2097152 (before seg1 w9)
    u16* a3Wu  = W2u + 2097152;       // 512x4096  (after seg2 conv done)
    u16* WAPu  = W2u + 4194304;       // 512x2048  = 1048576 (after seg3 conv)

    const bool big = ws_size >= (size_t)F_END * 4;

    // ---- dtype probe + zero accumulators (bufR..aspp + zero page) ----
    detect_kernel<<<1, 256, 0, stream>>>((const u16*)c1, flag);
    zero_kernel<<<1024, 256, 0, stream>>>(ws, 1114368);

    if (big) {
        // ---- refine(c1): repack then two 3x3 dil-2 convs on the fast engine
        xpose_bn<<<dim3(64, 4), 256, 0, stream>>>(c1, X1u, nullptr, nullptr,
                                                  flag, 1, 0, 256, 4096, 256, 0);
        xform_w9<<<dim3(1, 64), 256, 0, stream>>>(rf1_w, W9Ru, flag, 64, 256);
        conv_gemm<1><<<256, 256, 0, stream>>>(W9Ru, X1u, zp16, bufR,
                                              256, 64, 9, 2, 6, 4096, 1, 32, 32, 1);
        xpose_bn<<<dim3(64, 1), 256, 0, stream>>>(bufR, X1Bu, rf1_s, rf1_b,
                                                  flag, 0, 1, 64, 4096, 64, 0);
        xform_w9<<<dim3(1, 64), 256, 0, stream>>>(rf2_w, W9R2u, flag, 64, 64);
        conv_gemm<1><<<64, 256, 0, stream>>>(W9R2u, X1Bu, zp16, c1r,
                                             64, 64, 9, 2, 6, 4096, 1, 32, 32, 0);
        ep_bnrelu<<<1024, 256, 0, stream>>>(c1r, rf2_s, rf2_b, flag, 12, 262144);

        // ---- refine2: 1x1 conv on c2 (fast engine), then resize+bn ----
        xpose_bn<<<dim3(16, 8), 256, 0, stream>>>(c2, X1Cu, nullptr, nullptr,
                                                  flag, 1, 0, 512, 1024, 512, 0);
        xform_w1<<<128, 256, 0, stream>>>(r2_w, W1Ru, flag, 512, 0, 1, 9);
        conv_gemm<1><<<32, 256, 0, stream>>>(W1Ru, X1Cu, zp16, bufC,
                                             512, 64, 1, 0, 5, 1024, 1, 8, 128, 0);
        resize_bn<<<1024, 256, 0, stream>>>(bufC, c2r, r2_s, r2_b, flag, 1);

        attn_kernel<<<1024, 256, 0, stream>>>(c1r, c2r, att);

        gap_kernel<<<1024, 256, 0, stream>>>(x, flag, gapv);
        f4_kernel<<<128, 256, 0, stream>>>(a4_w, gapv, a4_s, a4_b, flag, f4c);
        f4con_kernel<<<128, 256, 0, stream>>>(ap_w, f4c, flag, f4con);

        // ---- one-time repack of x ----
        xpose_bn<<<dim3(16, 64), 256, 0, stream>>>(x, X2u, nullptr, nullptr,
                                                   flag, 1, 0, 4096, 1024, 4096, 0);

        // ---- seg0: 1x1 -> tmp -> T2all[:,0:512] ----
        zero_kernel<<<512, 256, 0, stream>>>(tmp, 524288);
        xform_w1<<<8192, 256, 0, stream>>>(a0_w, a0Wu, flag, 4096, 0, 1, 12);
        conv_gemm<2><<<256, 256, 0, stream>>>(a0Wu, X2u, zp16, tmp,
                                              4096, 512, 1, 0, 5, 1024, 4, 8, 512, 1);
        xpose_bn<<<dim3(16, 8), 256, 0, stream>>>(tmp, T2all, a0_s, a0_b,
                                                  flag, 0, 1, 512, 1024, 2048, 0);
        // ---- seg1: 3x3 d=12 ----
        zero_kernel<<<512, 256, 0, stream>>>(tmp, 524288);
        xform_w9<<<dim3(16, 512), 256, 0, stream>>>(a1_w, W2u, flag, 512, 4096);
        conv_gemm<2><<<512, 256, 0, stream>>>(W2u, X2u, zp16, tmp,
                                              4096, 512, 9, 12, 5, 1024, 4, 8, 256, 1);
        xpose_bn<<<dim3(16, 8), 256, 0, stream>>>(tmp, T2all, a1_s, a1_b,
                                                  flag, 0, 1, 512, 1024, 2048, 512);
        // ---- seg2: 3x3 d=24 ----
        zero_kernel<<<512, 256, 0, stream>>>(tmp, 524288);
        xform_w9<<<dim3(16, 512), 256, 0, stream>>>(a2_w, W2u, flag, 512, 4096);
        conv_gemm<2><<<512, 256, 0, stream>>>(W2u, X2u, zp16, tmp,
                                              4096, 512, 9, 24, 5, 1024, 4, 8, 256, 1);
        xpose_bn<<<dim3(16, 8), 256, 0, stream>>>(tmp, T2all, a2_s, a2_b,
                                                  flag, 0, 1, 512, 1024, 2048, 1024);
        // ---- seg3: 3x3 d=36 -> center tap only ----
        zero_kernel<<<512, 256, 0, stream>>>(tmp, 524288);
        xform_w1<<<8192, 256, 0, stream>>>(a3_w, a3Wu, flag, 36864, 4, 9, 12);
        conv_gemm<2><<<256, 256, 0, stream>>>(a3Wu, X2u, zp16, tmp,
                                              4096, 512, 1, 0, 5, 1024, 4, 8, 512, 1);
        xpose_bn<<<dim3(16, 8), 256, 0, stream>>>(tmp, T2all, a3_s, a3_b,
                                                  flag, 0, 1, 512, 1024, 2048, 1536);
        // ---- fused ap: one 1x1 conv over K=2048 (segments 0..3) ----
        xform_w1<<<4096, 256, 0, stream>>>(ap_w, WAPu, flag, 2560, 0, 1, 11);
        conv_gemm<2><<<256, 256, 0, stream>>>(WAPu, T2all, zp16, aspp,
                                              2048, 512, 1, 0, 5, 1024, 4, 8, 256, 1);
        // ---- ASPP epilogue ----
        ep_aspp<<<2048, 256, 0, stream>>>(aspp, f4con, ap_s, ap_b, flag);
    } else {
        // ---- fallback: old engine end-to-end ----
        conv_mfma<<<dim3(1, 32, 4), 256, 0, stream>>>(rf1_w, c1, bufR, flag, 1,
                                                      256, 256 * 9, 9, 0, 9, 2, 6);
        ep_bnrelu<<<1024, 256, 0, stream>>>(bufR, rf1_s, rf1_b, flag, 12, 262144);
        conv_mfma<<<dim3(1, 32, 2), 256, 0, stream>>>(rf2_w, bufR, c1r, flag, 0,
                                                      64, 64 * 9, 9, 0, 9, 2, 6);
        ep_bnrelu<<<1024, 256, 0, stream>>>(c1r, rf2_s, rf2_b, flag, 12, 262144);
        conv_mfma<<<dim3(1, 8, 4), 256, 0, stream>>>(r2_w, c2, bufC, flag, 1,
                                                     512, 512, 1, 0, 1, 0, 5);
        resize_bn<<<1024, 256, 0, stream>>>(bufC, c2r, r2_s, r2_b, flag, 1);
        attn_kernel<<<1024, 256, 0, stream>>>(c1r, c2r, att);
        gap_kernel<<<1024, 256, 0, stream>>>(x, flag, gapv);
        f4_kernel<<<128, 256, 0, stream>>>(a4_w, gapv, a4_s, a4_b, flag, f4c);
        f4con_kernel<<<128, 256, 0, stream>>>(ap_w, f4c, flag, f4con);

        zero_kernel<<<512, 256, 0, stream>>>(tmp, 524288);
        conv_mfma<<<dim3(8, 8, 4), 256, 0, stream>>>(a0_w, x, tmp, flag, 1,
                                                     4096, 4096, 1, 0, 1, 0, 5);
        ep_bnrelu<<<2048, 256, 0, stream>>>(tmp, a0_s, a0_b, flag, 10, 524288);
        conv_mfma<<<dim3(8, 8, 2), 256, 0, stream>>>(ap_w, tmp, aspp, flag, 0,
                                                     512, 2560, 1, 0, 1, 0, 5);
        zero_kernel<<<512, 256, 0, stream>>>(tmp, 524288);
        conv_mfma<<<dim3(8, 8, 8), 256, 0, stream>>>(a1_w, x, tmp, flag, 1,
                                                     4096, 4096 * 9, 9, 0, 9, 12, 5);
        ep_bnrelu<<<2048, 256, 0, stream>>>(tmp, a1_s, a1_b, flag, 10, 524288);
        conv_mfma<<<dim3(8, 8, 2), 256, 0, stream>>>(ap_w, tmp, aspp, flag, 0,
                                                     512, 2560, 1, 512, 1, 0, 5);
        zero_kernel<<<512, 256, 0, stream>>>(tmp, 524288);
        conv_mfma<<<dim3(8, 8, 8), 256, 0, stream>>>(a2_w, x, tmp, flag, 1,
                                                     4096, 4096 * 9, 9, 0, 9, 24, 5);
        ep_bnrelu<<<2048, 256, 0, stream>>>(tmp, a2_s, a2_b, flag, 10, 524288);
        conv_mfma<<<dim3(8, 8, 2), 256, 0, stream>>>(ap_w, tmp, aspp, flag, 0,
                                                     512, 2560, 1, 1024, 1, 0, 5);
        zero_kernel<<<512, 256, 0, stream>>>(tmp, 524288);
        conv_mfma<<<dim3(8, 8, 4), 256, 0, stream>>>(a3_w, x, tmp, flag, 1,
                                                     4096, 4096 * 9, 9, 4, 1, 0, 5);
        ep_bnrelu<<<2048, 256, 0, stream>>>(tmp, a3_s, a3_b, flag, 10, 524288);
        conv_mfma<<<dim3(8, 8, 2), 256, 0, stream>>>(ap_w, tmp, aspp, flag, 0,
                                                     512, 2560, 1, 1536, 1, 0, 5);
        ep_aspp<<<2048, 256, 0, stream>>>(aspp, f4con, ap_s, ap_b, flag);
    }

    // ---- tail: c6 on 32x32, resize to 64x64, attention aggregation ----
    vs_kernel<<<dim3(4, 19), 256, 0, stream>>>(aspp, c6_w, flag, Vs);
    resize_bn<<<304, 256, 0, stream>>>(Vs, V, nullptr, nullptr, flag, 0);
    final_kernel<<<304, 256, 0, stream>>>(att, V, c6_b, flag, d_out);
}

// Round 5
// 670.637 us; speedup vs baseline: 2.5148x; 1.0041x over previous
//
#include <hip/hip_runtime.h>
#include <hip/hip_bf16.h>

// ---------------------------------------------------------------------------
// up_deeplabv3Head — round 8: round-7 (tiled staging layouts) with the
// W-staging loop-bound bug fixed (MF rounds, not 2*MF — the W LDS image is
// MF*4096 bytes; the overflow corrupted the next pipeline buffer and read
// past the k-slab). X2 -> [K/32][P][32], W2 -> [tap][K/32][O][32] bf16 so
// every stage is contiguous. 3-buffer depth-2 pipeline, counted vmcnt,
// raw s_barrier + sched_barrier(0), setprio around MFMA.
// ---------------------------------------------------------------------------

typedef unsigned short u16;
typedef short bf16x8 __attribute__((ext_vector_type(8)));
typedef float f32x4  __attribute__((ext_vector_type(4)));
typedef u16   u16x8  __attribute__((ext_vector_type(8)));

__device__ __forceinline__ float bf2f(u16 u) {
    return __uint_as_float(((unsigned int)u) << 16);
}
__device__ __forceinline__ u16 f2bf(float f) {   // round-to-nearest-even
    unsigned u = __float_as_uint(f);
    return (u16)((u + 0x7FFFu + ((u >> 16) & 1u)) >> 16);
}
// flag f32: 1 -> storage fp32, 0 -> storage bf16
__device__ __forceinline__ float loadv(const void* p, long i, int f32) {
    return f32 ? ((const float*)p)[i] : bf2f(((const u16*)p)[i]);
}
__device__ __forceinline__ u16 loadbf(const void* p, long i, int f32) {
    return f32 ? f2bf(((const float*)p)[i]) : ((const u16*)p)[i];
}

__device__ __forceinline__ void gload16(const u16* g, u16* l) {
    __builtin_amdgcn_global_load_lds(
        (const __attribute__((address_space(1))) unsigned int*)(g),
        (__attribute__((address_space(3))) unsigned int*)(l), 16, 0, 0);
}

// ---------------------------------------------------------------------------
// dtype probe (verified): bf16-stored N(0,1) has ~0 large-exponent words.
// ---------------------------------------------------------------------------
__global__ __launch_bounds__(256) void detect_kernel(
    const u16* __restrict__ c1, int* __restrict__ flag)
{
    __shared__ int cnt;
    if (threadIdx.x == 0) cnt = 0;
    __syncthreads();
    int local = 0;
    for (int i = threadIdx.x; i < 16384; i += 256) {
        u16 u = c1[i];
        if ((u & 0x7F80) >= 0x4F00) local++;
    }
    atomicAdd(&cnt, local);
    __syncthreads();
    if (threadIdx.x == 0) flag[0] = (cnt > 256) ? 1 : 0;
}

__global__ __launch_bounds__(256) void zero_kernel(float* __restrict__ p, int n)
{
    for (int g = blockIdx.x * 256 + threadIdx.x; g < n; g += gridDim.x * 256)
        p[g] = 0.f;
}

// ---------------------------------------------------------------------------
// Repack kernels: tiled GEMM-staging layouts.
//   X: dst[((k>>5)*P + p)*32 + (k&31)]
//   W: dst[((t*(K/32) + (k>>5))*O + o)*32 + (k&31)]
// ---------------------------------------------------------------------------

// src [C][P] (f32 if !flagged, else flag-dtype) -> tiled dst at k-offset coff.
// Optional fused bn+relu per channel. Grid (P/64, C/64).
__global__ __launch_bounds__(256) void xpose_bn(
    const void* __restrict__ src, u16* __restrict__ dst,
    const void* __restrict__ s, const void* __restrict__ b,
    const int* __restrict__ flag, int flagged, int dobn, int C, int P, int coff)
{
    __shared__ u16 T[64][72];
    const int fl = flag[0];
    const int srcf32 = flagged ? fl : 1;
    const int p0 = blockIdx.x * 64, c0 = blockIdx.y * 64;
    const int t = threadIdx.x;
    {
        int c = t >> 2, pq = (t & 3) * 16;
        float sc = 1.f, bc = 0.f;
        if (dobn) { sc = loadv(s, c0 + c, fl); bc = loadv(b, c0 + c, fl); }
        const long sb = (long)(c0 + c) * P + p0 + pq;
        if (srcf32) {
            const float* sp = (const float*)src + sb;
#pragma unroll
            for (int i = 0; i < 16; i += 4) {
                float4 v = *(const float4*)(sp + i);
                float vv[4] = {v.x, v.y, v.z, v.w};
#pragma unroll
                for (int j = 0; j < 4; j++) {
                    float u = vv[j];
                    if (dobn) u = fmaxf(u * sc + bc, 0.f);
                    T[pq + i + j][c] = f2bf(u);
                }
            }
        } else {
            const u16* sp = (const u16*)src + sb;
#pragma unroll
            for (int i = 0; i < 16; i++) T[pq + i][c] = sp[i];
        }
    }
    __syncthreads();
    {
        int p = t >> 2, cq = (t & 3) * 16;
        u16x8 v0, v1;
#pragma unroll
        for (int i = 0; i < 8; i++) { v0[i] = T[p][cq + i]; v1[i] = T[p][cq + 8 + i]; }
        const int cabs = coff + c0 + cq;
        const long base = ((long)(cabs >> 5) * P + (p0 + p)) * 32 + (cabs & 31);
        *(u16x8*)&dst[base] = v0;
        *(u16x8*)&dst[base + 8] = v1;
    }
}

// w [O][C][9] -> tiled W9. Grid (ceil(C/256), O).
__global__ __launch_bounds__(256) void xform_w9(
    const void* __restrict__ w, u16* __restrict__ W9, const int* __restrict__ flag,
    int O, int C)
{
    const int f32 = flag[0];
    const int o = blockIdx.y;
    const int c = blockIdx.x * 256 + threadIdx.x;
    if (c >= C) return;
    const long src = ((long)o * C + c) * 9;
    u16 v[9];
    if (f32) {
        const float* p = (const float*)w + src;
#pragma unroll
        for (int j = 0; j < 9; j++) v[j] = f2bf(p[j]);
    } else {
        const u16* p = (const u16*)w + src;
#pragma unroll
        for (int j = 0; j < 9; j++) v[j] = p[j];
    }
    const int C32 = C >> 5;
#pragma unroll
    for (int j = 0; j < 9; j++)
        W9[((long)(j * C32 + (c >> 5)) * O + o) * 32 + (c & 31)] = v[j];
}

// 1-plane extract to tiled layout: element w[o*ldi + off + c*st].
// Grid O*C/256, C = 1<<logC.
__global__ __launch_bounds__(256) void xform_w1(
    const void* __restrict__ w, u16* __restrict__ Wo, const int* __restrict__ flag,
    int ldi, int off, int st, int logC, int O)
{
    const int f32 = flag[0];
    long g = (long)blockIdx.x * 256 + threadIdx.x;
    long o = g >> logC;
    int c = (int)(g & ((1 << logC) - 1));
    u16 v = loadbf(w, o * ldi + off + (long)c * st, f32);
    Wo[((long)(c >> 5) * O + o) * 32 + (c & 31)] = v;
}

// ---------------------------------------------------------------------------
// conv_gemm<MF>: OUT[o,p] += sum_{t in mask, c} W[t,o,c] * X[p+shift(t),c]
// Tile: (MF*64) o x 128 px, 4 waves. Tiled operands -> each stage is one
// contiguous 8KB (X) / MF*4KB (W) chunk; per-lane source pre-swizzled with
// byte ^= ((byte>>7)&3)<<4, linear LDS dest. 3-buffer depth-2 pipeline,
// counted vmcnt (L = MF+2 loads/stage; wait leaves only next stage in
// flight), raw s_barrier + sched_barrier(0), setprio around MFMA.
// 1-D grid, XCD-aware decode. Split-K + fp32 atomicAdd (OUT pre-zeroed).
// ---------------------------------------------------------------------------
template<int MF>
__global__ __launch_bounds__(256, 4) void conv_gemm(
    const u16* __restrict__ W2, const u16* __restrict__ X2,
    const u16* __restrict__ zpage, float* __restrict__ OUT,
    int K, int O, int taps, int d, int logIW, int P,
    int nbo, int nbp, int kcs, int swz)
{
    __shared__ __align__(16) u16 Ws[3][MF * 2048];
    __shared__ __align__(16) u16 Xs[3][4096];

    const int tid = threadIdx.x;
    int bo, bp, bz;
    {
        int pid = blockIdx.x;
        if (swz) {
            int xcd = pid & 7, j = pid >> 3;
            bp = j % nbp;
            int g = j / nbp;
            int G = xcd + 8 * g;
            bo = G % nbo; bz = G / nbo;
        } else {
            bp = pid % nbp;
            int q = pid / nbp;
            bo = q % nbo; bz = q / nbo;
        }
    }
    const int kb = bz * kcs;
    const int IW = 1 << logIW;

    const int wave = tid >> 6, lane = tid & 63;
    const int quad = lane >> 4, l15 = lane & 15;

    // uniform valid-tap mask over this tile's row band
    int mask = 1;
    if (taps == 9) {
        const int rb = 128 >> logIW;
        const int ty0 = bp * rb;
        mask = 0;
        for (int t = 0; t < 9; t++) {
            int dy = (t / 3 - 1) * d;
            if (ty0 + rb - 1 + dy >= 0 && ty0 + dy < IW) mask |= (1 << t);
        }
    }
    const int nIt = (kcs >> 5) * __popc(mask);

    // per-thread staging decode: LDS dest byte bb (linear) sources logical
    // byte l = bb ^ swz(bb); tiled global layout == logical LDS layout.
    // W image: MF*4096 bytes -> MF load rounds of 256thr x 16B.
    int lW[MF];
#pragma unroll
    for (int li = 0; li < MF; li++) {
        int bb = li * 4096 + tid * 16;
        lW[li] = bb ^ (((bb >> 7) & 3) << 4);
    }
    // X image: 8192 bytes -> 2 load rounds.
    int xr[2], xoff[2];
#pragma unroll
    for (int li = 0; li < 2; li++) {
        int bb = li * 4096 + tid * 16;
        int l = bb ^ (((bb >> 7) & 3) << 4);
        xr[li] = l >> 6;            // pixel row within 128-tile
        xoff[li] = (l & 63) >> 1;   // u16 offset within 32-k row
    }

    const int K32 = K >> 5;

    f32x4 acc[MF][8];
#pragma unroll
    for (int mi = 0; mi < MF; mi++)
#pragma unroll
        for (int j = 0; j < 8; j++) {
            f32x4 z = {0.f, 0.f, 0.f, 0.f};
            acc[mi][j] = z;
        }

    int arow[MF];
#pragma unroll
    for (int mi = 0; mi < MF; mi++) {
        int ao = (wave * (MF * 16) + mi * 16 + l15) * 64 + quad * 16;
        arow[mi] = ao ^ (((ao >> 7) & 3) << 4);
    }

    int tt = __ffs(mask) - 1;
    int kc = kb;

    auto STAGE = [&](int buf) {
        int dy = 0, dx = 0;
        if (taps == 9) { dy = (tt / 3 - 1) * d; dx = (tt % 3 - 1) * d; }
        const long wb = ((long)(tt * K32 + (kc >> 5)) * O + bo * (MF * 64)) * 32;
#pragma unroll
        for (int li = 0; li < MF; li++)
            gload16(W2 + wb + (lW[li] >> 1), &Ws[buf][li * 2048 + tid * 8]);
        const long xslab = (long)(kc >> 5) * P * 32;
#pragma unroll
        for (int li = 0; li < 2; li++) {
            int pg = bp * 128 + xr[li];
            const u16* src;
            if (taps == 9) {
                int yy = (pg >> logIW) + dy, xx = (pg & (IW - 1)) + dx;
                src = ((unsigned)yy < (unsigned)IW && (unsigned)xx < (unsigned)IW)
                    ? X2 + xslab + (long)((yy << logIW) + xx) * 32 + xoff[li] : zpage;
            } else {
                src = X2 + xslab + (long)pg * 32 + xoff[li];
            }
            gload16(src, &Xs[buf][li * 2048 + tid * 8]);
        }
        int rem = mask >> (tt + 1);
        if (rem) tt += __ffs(rem);
        else { tt = __ffs(mask) - 1; kc += 32; }
    };

    // prologue: depth-2 prefetch
    STAGE(0);
    if (nIt > 1) STAGE(1);

    for (int i = 0; i < nIt; i++) {
        // wait for current stage; leave only the next stage's loads in flight
        const int ex = nIt - 1 - i;
        if constexpr (MF == 2) {
            if (ex >= 1) asm volatile("s_waitcnt vmcnt(4)" ::: "memory");
            else         asm volatile("s_waitcnt vmcnt(0)" ::: "memory");
        } else {
            if (ex >= 1) asm volatile("s_waitcnt vmcnt(3)" ::: "memory");
            else         asm volatile("s_waitcnt vmcnt(0)" ::: "memory");
        }
        __builtin_amdgcn_s_barrier();
        __builtin_amdgcn_sched_barrier(0);   // nothing crosses the barrier

        const int cur = i % 3;
        bf16x8 a[MF];
#pragma unroll
        for (int mi = 0; mi < MF; mi++)
            a[mi] = *(const bf16x8*)&Ws[cur][arow[mi] >> 1];
        __builtin_amdgcn_s_setprio(1);
#pragma unroll
        for (int j = 0; j < 8; j++) {
            int boff = (j * 16 + l15) * 64 + quad * 16;
            boff ^= ((boff >> 7) & 3) << 4;
            bf16x8 b = *(const bf16x8*)&Xs[cur][boff >> 1];
#pragma unroll
            for (int mi = 0; mi < MF; mi++)
                acc[mi][j] = __builtin_amdgcn_mfma_f32_16x16x32_bf16(a[mi], b, acc[mi][j], 0, 0, 0);
        }
        __builtin_amdgcn_s_setprio(0);
        if (i + 2 < nIt) STAGE((i + 2) % 3);
    }

#pragma unroll
    for (int mi = 0; mi < MF; mi++)
#pragma unroll
        for (int j = 0; j < 8; j++) {
            int pgl = bp * 128 + j * 16 + l15;
            long ob = (long)(bo * (MF * 64) + wave * (MF * 16) + mi * 16 + quad * 4);
#pragma unroll
            for (int r = 0; r < 4; r++)
                atomicAdd(&OUT[(ob + r) * P + pgl], acc[mi][j][r]);
        }
}

// ---------------------------------------------------------------------------
// Old general MFMA conv (small-workspace fallback path only)
// ---------------------------------------------------------------------------
__global__ __launch_bounds__(256) void conv_mfma(
    const void* __restrict__ W, const void* __restrict__ X, float* __restrict__ OUT,
    const int* __restrict__ flag, int x_ext,
    int K, int wrow, int wstride, int woff, int taps, int d, int logIW)
{
    __shared__ __align__(16) u16 Ws[64 * 40];
    __shared__ __align__(16) u16 Xs[128 * 40];

    const int IW = 1 << logIW;
    const int NP = IW * IW;
    const int wf32 = flag[0];
    const int xf32 = x_ext ? wf32 : 1;

    const int tid = threadIdx.x;
    const int bo = blockIdx.x, bp = blockIdx.y;
    const int kcs = K / gridDim.z;
    const int kb = blockIdx.z * kcs;

    const int w_o = tid >> 2, w_kg = (tid & 3) * 8;
    const int x_p = tid >> 1, x_kg = (tid & 1) * 16;
    const int pg  = bp * 128 + x_p;
    const int py  = pg >> logIW, px = pg & (IW - 1);
    const int ty0 = (bp * 128) >> logIW;
    const int ty1 = ty0 + (128 >> logIW) - 1;

    const int wave = tid >> 6, lane = tid & 63;
    const int quad = lane >> 4, l15 = lane & 15;

    f32x4 acc[8];
#pragma unroll
    for (int j = 0; j < 8; j++) {
        f32x4 z = {0.f, 0.f, 0.f, 0.f};
        acc[j] = z;
    }

    const long wbase_o = (long)(bo * 64 + w_o) * wrow + woff;

    for (int kc = kb; kc < kb + kcs; kc += 32) {
        for (int t = 0; t < taps; t++) {
            int dy = 0, dx = 0, wt = 0;
            if (taps == 9) { dy = (t / 3 - 1) * d; dx = (t % 3 - 1) * d; wt = t; }
            if (ty1 + dy < 0 || ty0 + dy >= IW) continue;

            {
                u16 tv[8];
                if (wstride == 1) {
                    long idx = wbase_o + kc + w_kg;
                    if (wf32) {
                        float4 v0 = *(const float4*)((const float*)W + idx);
                        float4 v1 = *(const float4*)((const float*)W + idx + 4);
                        tv[0] = f2bf(v0.x); tv[1] = f2bf(v0.y);
                        tv[2] = f2bf(v0.z); tv[3] = f2bf(v0.w);
                        tv[4] = f2bf(v1.x); tv[5] = f2bf(v1.y);
                        tv[6] = f2bf(v1.z); tv[7] = f2bf(v1.w);
                    } else {
                        ushort4 v0 = *(const ushort4*)((const u16*)W + idx);
                        ushort4 v1 = *(const ushort4*)((const u16*)W + idx + 4);
                        tv[0] = v0.x; tv[1] = v0.y; tv[2] = v0.z; tv[3] = v0.w;
                        tv[4] = v1.x; tv[5] = v1.y; tv[6] = v1.z; tv[7] = v1.w;
                    }
                } else {
                    long idx = wbase_o + wt + (long)(kc + w_kg) * 9;
#pragma unroll
                    for (int i = 0; i < 8; i++)
                        tv[i] = loadbf(W, idx + (long)i * 9, wf32);
                }
                *(ushort4*)&Ws[w_o * 40 + w_kg]     = make_ushort4(tv[0], tv[1], tv[2], tv[3]);
                *(ushort4*)&Ws[w_o * 40 + w_kg + 4] = make_ushort4(tv[4], tv[5], tv[6], tv[7]);
            }
            {
                int yy = py + dy, xv = px + dx;
                bool ok = ((unsigned)yy < (unsigned)IW) && ((unsigned)xv < (unsigned)IW);
                u16 tv[16];
                if (ok) {
                    long idx = (long)(kc + x_kg) * NP + yy * IW + xv;
                    if (xf32) {
#pragma unroll
                        for (int i = 0; i < 16; i++)
                            tv[i] = f2bf(((const float*)X)[idx + (long)i * NP]);
                    } else {
#pragma unroll
                        for (int i = 0; i < 16; i++)
                            tv[i] = ((const u16*)X)[idx + (long)i * NP];
                    }
                } else {
#pragma unroll
                    for (int i = 0; i < 16; i++) tv[i] = 0;
                }
                *(ushort4*)&Xs[x_p * 40 + x_kg]      = make_ushort4(tv[0], tv[1], tv[2], tv[3]);
                *(ushort4*)&Xs[x_p * 40 + x_kg + 4]  = make_ushort4(tv[4], tv[5], tv[6], tv[7]);
                *(ushort4*)&Xs[x_p * 40 + x_kg + 8]  = make_ushort4(tv[8], tv[9], tv[10], tv[11]);
                *(ushort4*)&Xs[x_p * 40 + x_kg + 12] = make_ushort4(tv[12], tv[13], tv[14], tv[15]);
            }
            __syncthreads();
            {
                bf16x8 a = *(const bf16x8*)&Ws[(wave * 16 + l15) * 40 + quad * 8];
#pragma unroll
                for (int j = 0; j < 8; j++) {
                    bf16x8 b = *(const bf16x8*)&Xs[(j * 16 + l15) * 40 + quad * 8];
                    acc[j] = __builtin_amdgcn_mfma_f32_16x16x32_bf16(a, b, acc[j], 0, 0, 0);
                }
            }
            __syncthreads();
        }
    }

#pragma unroll
    for (int j = 0; j < 8; j++) {
        int pgl = bp * 128 + j * 16 + l15;
        long ob = (long)(bo * 64 + wave * 16 + quad * 4);
#pragma unroll
        for (int r = 0; r < 4; r++)
            atomicAdd(&OUT[(ob + r) * NP + pgl], acc[j][r]);
    }
}

// bn+relu in place over (C, N) f32, N = 2^logN
__global__ __launch_bounds__(256) void ep_bnrelu(
    float* __restrict__ buf, const void* __restrict__ s, const void* __restrict__ b,
    const int* __restrict__ flag, int logN, int total)
{
    int f32 = flag[0];
    int g = blockIdx.x * 256 + threadIdx.x;
    if (g >= total) return;
    int c = g >> logN;
    float v = buf[g] * loadv(s, c, f32) + loadv(b, c, f32);
    buf[g] = fmaxf(v, 0.f);
}

__global__ __launch_bounds__(256) void ep_aspp(
    float* __restrict__ buf, const float* __restrict__ f4con,
    const void* __restrict__ s, const void* __restrict__ b, const int* __restrict__ flag)
{
    int f32 = flag[0];
    int g = blockIdx.x * 256 + threadIdx.x;
    int c = g >> 10;
    float v = (buf[g] + f4con[c]) * loadv(s, c, f32) + loadv(b, c, f32);
    buf[g] = fmaxf(v, 0.f);
}

__global__ __launch_bounds__(256) void resize_bn(
    const float* __restrict__ in, float* __restrict__ out,
    const void* __restrict__ s, const void* __restrict__ b,
    const int* __restrict__ flag, int dobn)
{
    int g = blockIdx.x * 256 + threadIdx.x;
    int c = g >> 12, p = g & 4095;
    int oy = p >> 6, ox = p & 63;
    const float r = 31.0f / 63.0f;
    float tyf = oy * r, txf = ox * r;
    int y0 = (int)tyf, x0 = (int)txf;
    float fy = tyf - y0, fx = txf - x0;
    int y1 = y0 + 1 > 31 ? 31 : y0 + 1;
    int x1 = x0 + 1 > 31 ? 31 : x0 + 1;
    const float* pc = in + c * 1024;
    float v00 = pc[y0 * 32 + x0], v01 = pc[y0 * 32 + x1];
    float v10 = pc[y1 * 32 + x0], v11 = pc[y1 * 32 + x1];
    float v = (1.f - fy) * ((1.f - fx) * v00 + fx * v01) +
              fy * ((1.f - fx) * v10 + fx * v11);
    if (dobn) v = fmaxf(v * loadv(s, c, flag[0]) + loadv(b, c, flag[0]), 0.f);
    out[g] = v;
}

__global__ __launch_bounds__(256) void attn_kernel(
    const float* __restrict__ c1r, const float* __restrict__ c2r, float* __restrict__ att)
{
    int tid = threadIdx.x;
    int p = blockIdx.x * 4 + (tid >> 6);
    int lane = tid & 63;
    int y = p >> 6, x = p & 63;
    float a = c1r[lane * 4096 + p];
    float e[9];
#pragma unroll
    for (int ky = 0; ky < 3; ky++)
#pragma unroll
        for (int kx = 0; kx < 3; kx++) {
            int yy = y + 2 * (ky - 1), xx = x + 2 * (kx - 1);
            float v = 0.f;
            if (yy >= 0 && yy < 64 && xx >= 0 && xx < 64)
                v = a * c2r[lane * 4096 + yy * 64 + xx];
#pragma unroll
            for (int off = 32; off; off >>= 1) v += __shfl_xor(v, off);
            e[ky * 3 + kx] = v;
        }
    float m = e[0];
#pragma unroll
    for (int k = 1; k < 9; k++) m = fmaxf(m, e[k]);
    float ssum = 0.f;
#pragma unroll
    for (int k = 0; k < 9; k++) ssum += __expf(e[k] - m);
    if (lane < 9) {
        float mye = e[0];
#pragma unroll
        for (int k = 1; k < 9; k++)
            if (lane == k) mye = e[k];
        att[p * 9 + lane] = __expf(mye - m) / ssum;
    }
}

__global__ __launch_bounds__(256) void gap_kernel(
    const void* __restrict__ x, const int* __restrict__ flag, float* __restrict__ gap)
{
    int f32 = flag[0];
    int tid = threadIdx.x;
    int c = blockIdx.x * 4 + (tid >> 6);
    int lane = tid & 63;
    long base = (long)c * 1024;
    float ssum = 0.f;
#pragma unroll
    for (int i = 0; i < 16; i++) ssum += loadv(x, base + lane + i * 64, f32);
#pragma unroll
    for (int off = 32; off; off >>= 1) ssum += __shfl_xor(ssum, off);
    if (lane == 0) gap[c] = ssum * (1.0f / 1024.0f);
}

__global__ __launch_bounds__(256) void f4_kernel(
    const void* __restrict__ w, const float* __restrict__ gap,
    const void* __restrict__ s, const void* __restrict__ b,
    const int* __restrict__ flag, float* __restrict__ f4c)
{
    int f32 = flag[0];
    int tid = threadIdx.x;
    int o = blockIdx.x * 4 + (tid >> 6);
    int lane = tid & 63;
    long base = (long)o * 4096;
    float ssum = 0.f;
#pragma unroll
    for (int i = 0; i < 64; i++)
        ssum += loadv(w, base + lane + i * 64, f32) * gap[lane + i * 64];
#pragma unroll
    for (int off = 32; off; off >>= 1) ssum += __shfl_xor(ssum, off);
    if (lane == 0) f4c[o] = fmaxf(ssum * loadv(s, o, f32) + loadv(b, o, f32), 0.f);
}

__global__ __launch_bounds__(256) void f4con_kernel(
    const void* __restrict__ ap_w, const float* __restrict__ f4c,
    const int* __restrict__ flag, float* __restrict__ f4con)
{
    int f32 = flag[0];
    int tid = threadIdx.x;
    int o = blockIdx.x * 4 + (tid >> 6);
    int lane = tid & 63;
    long base = (long)o * 2560 + 2048;
    float ssum = 0.f;
#pragma unroll
    for (int i = 0; i < 8; i++)
        ssum += loadv(ap_w, base + lane + i * 64, f32) * f4c[lane + i * 64];
#pragma unroll
    for (int off = 32; off; off >>= 1) ssum += __shfl_xor(ssum, off);
    if (lane == 0) f4con[o] = ssum;
}

__global__ __launch_bounds__(256) void vs_kernel(
    const float* __restrict__ aspp, const void* __restrict__ w,
    const int* __restrict__ flag, float* __restrict__ Vs)
{
    int f32 = flag[0];
    int p = blockIdx.x * 256 + threadIdx.x;
    int q = blockIdx.y;
    long wb = (long)q * 512;
    float a0 = 0.f, a1 = 0.f, a2 = 0.f, a3 = 0.f;
    for (int c = 0; c < 512; c += 4) {
        a0 = fmaf(loadv(w, wb + c + 0, f32), aspp[(c + 0) * 1024 + p], a0);
        a1 = fmaf(loadv(w, wb + c + 1, f32), aspp[(c + 1) * 1024 + p], a1);
        a2 = fmaf(loadv(w, wb + c + 2, f32), aspp[(c + 2) * 1024 + p], a2);
        a3 = fmaf(loadv(w, wb + c + 3, f32), aspp[(c + 3) * 1024 + p], a3);
    }
    Vs[q * 1024 + p] = (a0 + a1) + (a2 + a3);
}

__global__ __launch_bounds__(256) void final_kernel(
    const float* __restrict__ att, const float* __restrict__ V,
    const void* __restrict__ bias, const int* __restrict__ flag, void* __restrict__ out)
{
    int f32 = flag[0];
    int g = blockIdx.x * 256 + threadIdx.x;
    int q = g >> 12, p = g & 4095;
    int y = p >> 6, x = p & 63;
    const float* a = att + p * 9;
    const float* v = V + q * 4096;
    float acc = loadv(bias, q, f32);
#pragma unroll
    for (int ky = 0; ky < 3; ky++)
#pragma unroll
        for (int kx = 0; kx < 3; kx++) {
            int yy = y + 2 * (ky - 1), xx = x + 2 * (kx - 1);
            if (yy >= 0 && yy < 64 && xx >= 0 && xx < 64)
                acc += a[ky * 3 + kx] * v[yy * 64 + xx];
        }
    if (f32) ((float*)out)[g] = acc;
    else     ((__hip_bfloat16*)out)[g] = __float2bfloat16(acc);
}

// ---------------------------------------------------------------------------
// Host orchestration
// ---------------------------------------------------------------------------
extern "C" void kernel_launch(void* const* d_in, const int* in_sizes, int n_in,
                              void* d_out, int out_size, void* d_ws, size_t ws_size,
                              hipStream_t stream)
{
    const void* c1    = d_in[0];
    const void* c2    = d_in[1];
    const void* x     = d_in[2];
    const void* rf1_w = d_in[3];
    const void* rf1_s = d_in[4];
    const void* rf1_b = d_in[5];
    const void* rf2_w = d_in[6];
    const void* rf2_s = d_in[7];
    const void* rf2_b = d_in[8];
    const void* r2_w  = d_in[9];
    const void* r2_s  = d_in[10];
    const void* r2_b  = d_in[11];
    const void* a0_w  = d_in[12];
    const void* a0_s  = d_in[13];
    const void* a0_b  = d_in[14];
    const void* a1_w  = d_in[15];
    const void* a1_s  = d_in[16];
    const void* a1_b  = d_in[17];
    const void* a2_w  = d_in[18];
    const void* a2_s  = d_in[19];
    const void* a2_b  = d_in[20];
    const void* a3_w  = d_in[21];
    const void* a3_s  = d_in[22];
    const void* a3_b  = d_in[23];
    const void* a4_w  = d_in[24];
    const void* a4_s  = d_in[25];
    const void* a4_b  = d_in[26];
    const void* ap_w  = d_in[27];
    const void* ap_s  = d_in[28];
    const void* ap_b  = d_in[29];
    const void* c6_w  = d_in[30];
    const void* c6_b  = d_in[31];

    // ---- workspace layout (float slots); same F_END as rounds 4-7 ----
    const long F_BUFR = 0;          //  262144  rf1 out (64,4096)   [accum]
    const long F_C1R  = 262144;     //  262144  rf2 out (64,4096)   [accum]
    const long F_BUFC = 524288;     //   65536  r2 out (64,1024)    [accum]
    const long F_ASPP = 589824;     //  524288  ap out (512,1024)   [accum]
    const long F_ZP   = 1114112;    //     256  zero page (stays zero)
    const long F_TMP  = 1114368;    //  524288  ASPP branch [accum, reused x4]
    const long F_C2R  = 1638656;    //  262144
    const long F_ATT  = 1900800;    //   36864
    const long F_GAPV = 1937664;    //    4096
    const long F_F4C  = 1941760;    //     512
    const long F_F4CO = 1942272;    //     512
    const long F_VS   = 1942784;    //   19456
    const long F_V    = 1962240;    //   77824
    const long F_FLAG = 2040064;    //      64
    const long F_X2   = 2040128;    // 2097152 float-slots (tiled X, 1024px K=4096)
    const long F_W2   = 4137280;    // 9437184 float-slots (tiled 9-tap W 512x4096)
    const long F_W1   = 13574464;   // 1048576 float-slots -> T2all (tiled, 1024px K=2048)
    const long F_END  = 14623040;

    float* ws    = (float*)d_ws;
    float* bufR  = ws + F_BUFR;
    float* c1r   = ws + F_C1R;
    float* bufC  = ws + F_BUFC;
    float* aspp  = ws + F_ASPP;
    float* tmp   = ws + F_TMP;
    float* c2r   = ws + F_C2R;
    float* att   = ws + F_ATT;
    float* gapv  = ws + F_GAPV;
    float* f4c   = ws + F_F4C;
    float* f4con = ws + F_F4CO;
    float* Vs    = ws + F_VS;
    float* V     = ws + F_V;
    int*   flag  = (int*)(ws + F_FLAG);
    u16*   X2u   = (u16*)(ws + F_X2);
    u16*   W2u   = (u16*)(ws + F_W2);
    u16*   T2all = (u16*)(ws + F_W1);   // tiled [64][1024][32]
    const u16* zp16 = (const u16*)(ws + F_ZP);

    // sub-allocations inside W2u (idle until seg1) for the refine/r2 phase
    u16* X1u   = W2u;                 // tiled 4096px K=256 = 1048576 u16
    u16* W9Ru  = W2u + 1048576;       // 9x64x256  =  147456
    u16* X1Bu  = W2u + 1196032;       // tiled 4096px K=64 = 262144
    u16* W9R2u = W2u + 1458176;       // 9x64x64   =   36864
    u16* X1Cu  = W2u + 1495040;       // tiled 1024px K=512 = 524288
    u16* W1Ru  = W2u + 2019328;       // 64x512    =   32768
    // W2u re-use within ASPP stream (all sequential, stream-ordered):
    u16* a0Wu  = W2u;                 // 512x4096  = 2097152 (before seg1 w9)
    u16* a3Wu  = W2u + 2097152;       // 512x4096  (after seg2 conv done)
    u16* WAPu  = W2u + 4194304;       // 512x2048  = 1048576 (after seg3 conv)

    const bool big = ws_size >= (size_t)F_END * 4;

    // ---- dtype probe + zero accumulators (bufR..aspp + zero page) ----
    detect_kernel<<<1, 256, 0, stream>>>((const u16*)c1, flag);
    zero_kernel<<<1024, 256, 0, stream>>>(ws, 1114368);

    if (big) {
        // ---- refine(c1): repack then two 3x3 dil-2 convs on the fast engine
        xpose_bn<<<dim3(64, 4), 256, 0, stream>>>(c1, X1u, nullptr, nullptr,
                                                  flag, 1, 0, 256, 4096, 0);
        xform_w9<<<dim3(1, 64), 256, 0, stream>>>(rf1_w, W9Ru, flag, 64, 256);
        conv_gemm<1><<<256, 256, 0, stream>>>(W9Ru, X1u, zp16, bufR,
                                              256, 64, 9, 2, 6, 4096, 1, 32, 32, 1);
        xpose_bn<<<dim3(64, 1), 256, 0, stream>>>(bufR, X1Bu, rf1_s, rf1_b,
                                                  flag, 0, 1, 64, 4096, 0);
        xform_w9<<<dim3(1, 64), 256, 0, stream>>>(rf2_w, W9R2u, flag, 64, 64);
        conv_gemm<1><<<64, 256, 0, stream>>>(W9R2u, X1Bu, zp16, c1r,
                                             64, 64, 9, 2, 6, 4096, 1, 32, 32, 0);
        ep_bnrelu<<<1024, 256, 0, stream>>>(c1r, rf2_s, rf2_b, flag, 12, 262144);

        // ---- refine2: 1x1 conv on c2 (fast engine), then resize+bn ----
        xpose_bn<<<dim3(16, 8), 256, 0, stream>>>(c2, X1Cu, nullptr, nullptr,
                                                  flag, 1, 0, 512, 1024, 0);
        xform_w1<<<128, 256, 0, stream>>>(r2_w, W1Ru, flag, 512, 0, 1, 9, 64);
        conv_gemm<1><<<32, 256, 0, stream>>>(W1Ru, X1Cu, zp16, bufC,
                                             512, 64, 1, 0, 5, 1024, 1, 8, 128, 0);
        resize_bn<<<1024, 256, 0, stream>>>(bufC, c2r, r2_s, r2_b, flag, 1);

        attn_kernel<<<1024, 256, 0, stream>>>(c1r, c2r, att);

        gap_kernel<<<1024, 256, 0, stream>>>(x, flag, gapv);
        f4_kernel<<<128, 256, 0, stream>>>(a4_w, gapv, a4_s, a4_b, flag, f4c);
        f4con_kernel<<<128, 256, 0, stream>>>(ap_w, f4c, flag, f4con);

        // ---- one-time repack of x ----
        xpose_bn<<<dim3(16, 64), 256, 0, stream>>>(x, X2u, nullptr, nullptr,
                                                   flag, 1, 0, 4096, 1024, 0);

        // ---- seg0: 1x1 -> tmp -> T2all k[0:512) ----
        zero_kernel<<<512, 256, 0, stream>>>(tmp, 524288);
        xform_w1<<<8192, 256, 0, stream>>>(a0_w, a0Wu, flag, 4096, 0, 1, 12, 512);
        conv_gemm<2><<<256, 256, 0, stream>>>(a0Wu, X2u, zp16, tmp,
                                              4096, 512, 1, 0, 5, 1024, 4, 8, 512, 1);
        xpose_bn<<<dim3(16, 8), 256, 0, stream>>>(tmp, T2all, a0_s, a0_b,
                                                  flag, 0, 1, 512, 1024, 0);
        // ---- seg1: 3x3 d=12 ----
        zero_kernel<<<512, 256, 0, stream>>>(tmp, 524288);
        xform_w9<<<dim3(16, 512), 256, 0, stream>>>(a1_w, W2u, flag, 512, 4096);
        conv_gemm<2><<<512, 256, 0, stream>>>(W2u, X2u, zp16, tmp,
                                              4096, 512, 9, 12, 5, 1024, 4, 8, 256, 1);
        xpose_bn<<<dim3(16, 8), 256, 0, stream>>>(tmp, T2all, a1_s, a1_b,
                                                  flag, 0, 1, 512, 1024, 512);
        // ---- seg2: 3x3 d=24 ----
        zero_kernel<<<512, 256, 0, stream>>>(tmp, 524288);
        xform_w9<<<dim3(16, 512), 256, 0, stream>>>(a2_w, W2u, flag, 512, 4096);
        conv_gemm<2><<<512, 256, 0, stream>>>(W2u, X2u, zp16, tmp,
                                              4096, 512, 9, 24, 5, 1024, 4, 8, 256, 1);
        xpose_bn<<<dim3(16, 8), 256, 0, stream>>>(tmp, T2all, a2_s, a2_b,
                                                  flag, 0, 1, 512, 1024, 1024);
        // ---- seg3: 3x3 d=36 -> center tap only ----
        zero_kernel<<<512, 256, 0, stream>>>(tmp, 524288);
        xform_w1<<<8192, 256, 0, stream>>>(a3_w, a3Wu, flag, 36864, 4, 9, 12, 512);
        conv_gemm<2><<<256, 256, 0, stream>>>(a3Wu, X2u, zp16, tmp,
                                              4096, 512, 1, 0, 5, 1024, 4, 8, 512, 1);
        xpose_bn<<<dim3(16, 8), 256, 0, stream>>>(tmp, T2all, a3_s, a3_b,
                                                  flag, 0, 1, 512, 1024, 1536);
        // ---- fused ap: one 1x1 conv over K=2048 (segments 0..3) ----
        xform_w1<<<4096, 256, 0, stream>>>(ap_w, WAPu, flag, 2560, 0, 1, 11, 512);
        conv_gemm<2><<<256, 256, 0, stream>>>(WAPu, T2all, zp16, aspp,
                                              2048, 512, 1, 0, 5, 1024, 4, 8, 256, 1);
        // ---- ASPP epilogue ----
        ep_aspp<<<2048, 256, 0, stream>>>(aspp, f4con, ap_s, ap_b, flag);
    } else {
        // ---- fallback: old engine end-to-end ----
        conv_mfma<<<dim3(1, 32, 4), 256, 0, stream>>>(rf1_w, c1, bufR, flag, 1,
                                                      256, 256 * 9, 9, 0, 9, 2, 6);
        ep_bnrelu<<<1024, 256, 0, stream>>>(bufR, rf1_s, rf1_b, flag, 12, 262144);
        conv_mfma<<<dim3(1, 32, 2), 256, 0, stream>>>(rf2_w, bufR, c1r, flag, 0,
                                                      64, 64 * 9, 9, 0, 9, 2, 6);
        ep_bnrelu<<<1024, 256, 0, stream>>>(c1r, rf2_s, rf2_b, flag, 12, 262144);
        conv_mfma<<<dim3(1, 8, 4), 256, 0, stream>>>(r2_w, c2, bufC, flag, 1,
                                                     512, 512, 1, 0, 1, 0, 5);
        resize_bn<<<1024, 256, 0, stream>>>(bufC, c2r, r2_s, r2_b, flag, 1);
        attn_kernel<<<1024, 256, 0, stream>>>(c1r, c2r, att);
        gap_kernel<<<1024, 256, 0, stream>>>(x, flag, gapv);
        f4_kernel<<<128, 256, 0, stream>>>(a4_w, gapv, a4_s, a4_b, flag, f4c);
        f4con_kernel<<<128, 256, 0, stream>>>(ap_w, f4c, flag, f4con);

        zero_kernel<<<512, 256, 0, stream>>>(tmp, 524288);
        conv_mfma<<<dim3(8, 8, 4), 256, 0, stream>>>(a0_w, x, tmp, flag, 1,
                                                     4096, 4096, 1, 0, 1, 0, 5);
        ep_bnrelu<<<2048, 256, 0, stream>>>(tmp, a0_s, a0_b, flag, 10, 524288);
        conv_mfma<<<dim3(8, 8, 2), 256, 0, stream>>>(ap_w, tmp, aspp, flag, 0,
                                                     512, 2560, 1, 0, 1, 0, 5);
        zero_kernel<<<512, 256, 0, stream>>>(tmp, 524288);
        conv_mfma<<<dim3(8, 8, 8), 256, 0, stream>>>(a1_w, x, tmp, flag, 1,
                                                     4096, 4096 * 9, 9, 0, 9, 12, 5);
        ep_bnrelu<<<2048, 256, 0, stream>>>(tmp, a1_s, a1_b, flag, 10, 524288);
        conv_mfma<<<dim3(8, 8, 2), 256, 0, stream>>>(ap_w, tmp, aspp, flag, 0,
                                                     512, 2560, 1, 512, 1, 0, 5);
        zero_kernel<<<512, 256, 0, stream>>>(tmp, 524288);
        conv_mfma<<<dim3(8, 8, 8), 256, 0, stream>>>(a2_w, x, tmp, flag, 1,
                                                     4096, 4096 * 9, 9, 0, 9, 24, 5);
        ep_bnrelu<<<2048, 256, 0, stream>>>(tmp, a2_s, a2_b, flag, 10, 524288);
        conv_mfma<<<dim3(8, 8, 2), 256, 0, stream>>>(ap_w, tmp, aspp, flag, 0,
                                                     512, 2560, 1, 1024, 1, 0, 5);
        zero_kernel<<<512, 256, 0, stream>>>(tmp, 524288);
        conv_mfma<<<dim3(8, 8, 4), 256, 0, stream>>>(a3_w, x, tmp, flag, 1,
                                                     4096, 4096 * 9, 9, 4, 1, 0, 5);
        ep_bnrelu<<<2048, 256, 0, stream>>>(tmp, a3_s, a3_b, flag, 10, 524288);
        conv_mfma<<<dim3(8, 8, 2), 256, 0, stream>>>(ap_w, tmp, aspp, flag, 0,
                                                     512, 2560, 1, 1536, 1, 0, 5);
        ep_aspp<<<2048, 256, 0, stream>>>(aspp, f4con, ap_s, ap_b, flag);
    }

    // ---- tail: c6 on 32x32, resize to 64x64, attention aggregation ----
    vs_kernel<<<dim3(4, 19), 256, 0, stream>>>(aspp, c6_w, flag, Vs);
    resize_bn<<<304, 256, 0, stream>>>(Vs, V, nullptr, nullptr, flag, 0);
    final_kernel<<<304, 256, 0, stream>>>(att, V, c6_b, flag, d_out);
}